// Round 9
// baseline (248.821 us; speedup 1.0000x reference)
//
#include <hip/hip_runtime.h>
#include <stdint.h>

// ---------- bf16 helpers (storage = unsigned short) ----------
__device__ __forceinline__ float b2f(unsigned short u) {
    union { uint32_t i; float f; } v; v.i = ((uint32_t)u) << 16; return v.f;
}
__device__ __forceinline__ unsigned short f2b(float f) {
    union { float f; uint32_t i; } v; v.f = f;
    uint32_t r = v.i + 0x7fffu + ((v.i >> 16) & 1u);   // RNE
    return (unsigned short)(r >> 16);
}

typedef __bf16 bf16x8 __attribute__((ext_vector_type(8)));
typedef float  f32x16 __attribute__((ext_vector_type(16)));

// ---------------------------------------------------------------------------
// build_T body: T[rm=(r1*16+n2)*16+m2][n3][m3] = sum_r2 c1[rm][r2]*c2[...]
// 524288 elems per layer (2048 blocks x 256; R3 lesson: never shrink).
// ---------------------------------------------------------------------------
template<int N3, int M3>
__device__ __forceinline__ void build_T_body(int e,
                                             const float* __restrict__ c1,
                                             const float* __restrict__ c2,
                                             float* __restrict__ T) {
    int m3 = e % M3;
    int t  = e / M3;
    int n3 = t % N3;
    int rm = t / N3;
    float s = 0.f;
#pragma unroll
    for (int r2 = 0; r2 < 16; ++r2)
        s += c1[rm * 16 + r2] * c2[(r2 * N3 + n3) * M3 + m3];
    T[e] = s;
}

// Fused stage-1: blocks [0,2048) -> T1, [2048,4096) -> T2,
// [4096,6144) -> cvt x (f32) -> xb (bf16).  Verified R5-R8.
__global__ __launch_bounds__(256)
void prep_stage1(const float* __restrict__ c11, const float* __restrict__ c12,
                 float* __restrict__ T1,
                 const float* __restrict__ c21, const float* __restrict__ c22,
                 float* __restrict__ T2,
                 const float* __restrict__ x, unsigned short* __restrict__ xb) {
    const int b = blockIdx.x;
    if (b < 2048) {
        build_T_body<8, 16>(b * 256 + threadIdx.x, c11, c12, T1);
    } else if (b < 4096) {
        build_T_body<16, 8>((b - 2048) * 256 + threadIdx.x, c21, c22, T2);
    } else {
        const int t = (b - 4096) * 256 + threadIdx.x;
        const float4* p = (const float4*)(x + (size_t)t * 8);
        float4 f0 = p[0], f1 = p[1];
        int4 o;
        o.x = (uint32_t)f2b(f0.x) | ((uint32_t)f2b(f0.y) << 16);
        o.y = (uint32_t)f2b(f0.z) | ((uint32_t)f2b(f0.w) << 16);
        o.z = (uint32_t)f2b(f1.x) | ((uint32_t)f2b(f1.y) << 16);
        o.w = (uint32_t)f2b(f1.z) | ((uint32_t)f2b(f1.w) << 16);
        ((int4*)xb)[t] = o;
    }
}

// ---------------------------------------------------------------------------
// build_W body: thread t = (((n1*M1+m1)*N2+n2)*M2+m2)*M3+m3.
// W[outRow=(m1*M2+m2)*M3+m3][K] (B^T layout, bf16), K = N1*N2*N3.
// ---------------------------------------------------------------------------
template<int N1, int N2, int N3, int M1, int M2, int M3>
__device__ __forceinline__ void build_W_body(int t,
                                             const float* __restrict__ c0,
                                             const float* __restrict__ T,
                                             unsigned short* __restrict__ W) {
    constexpr int K = N1 * N2 * N3;
    int m3 = t % M3;
    int m2 = (t / M3) % M2;
    int n2 = (t / (M3 * M2)) % N2;
    int m1 = (t / (M3 * M2 * N2)) % M1;
    int n1 =  t / (M3 * M2 * N2 * M1);

    float c0r[16];
    const float4* c0p = (const float4*)(c0 + (n1 * M1 + m1) * 16);
#pragma unroll
    for (int i = 0; i < 4; ++i) ((float4*)c0r)[i] = c0p[i];

    float acc[N3] = {};
#pragma unroll
    for (int r1 = 0; r1 < 16; ++r1) {
        const float* Tp = T + (size_t)(((r1 * 16 + n2) * 16 + m2) * N3) * M3 + m3;
#pragma unroll
        for (int n3 = 0; n3 < N3; ++n3)
            acc[n3] += c0r[r1] * Tp[n3 * M3];
    }

    unsigned short ob[N3];
#pragma unroll
    for (int n3 = 0; n3 < N3; ++n3) ob[n3] = f2b(acc[n3]);

    unsigned short* dst = W + (size_t)((m1 * M2 + m2) * M3 + m3) * K
                            + (n1 * N2 + n2) * N3;
#pragma unroll
    for (int c = 0; c < N3 / 8; ++c)
        ((int4*)dst)[c] = ((const int4*)ob)[c];
}

// Fused: blocks [0,2048) -> W1, [2048,3072) -> W2.  Verified R5-R8.
__global__ __launch_bounds__(256)
void build_W_both(const float* __restrict__ c10, const float* __restrict__ T1,
                  unsigned short* __restrict__ W1,
                  const float* __restrict__ c20, const float* __restrict__ T2,
                  unsigned short* __restrict__ W2) {
    const int b = blockIdx.x;
    if (b < 2048)
        build_W_body<8, 16, 8, 16, 16, 16>(b * 256 + threadIdx.x, c10, T1, W1);
    else
        build_W_body<16, 16, 16, 8, 16, 8>((b - 2048) * 256 + threadIdx.x, c20, T2, W2);
}

// Standalone (small-workspace fallback path only).
template<int N1, int N2, int N3, int M1, int M2, int M3>
__global__ __launch_bounds__(256)
void build_W(const float* __restrict__ c0, const float* __restrict__ T,
             unsigned short* __restrict__ W) {
    build_W_body<N1, N2, N3, M1, M2, M3>(blockIdx.x * 256 + threadIdx.x, c0, T, W);
}

// ---------------------------------------------------------------------------
// bias_fill: out[r][c] = bias[c]  (f32, 1024 cols = 256 float4 per row)
// Runs AFTER GEMM1 (d_out scratch T1/T2/xb is dead by then).
// ---------------------------------------------------------------------------
__global__ __launch_bounds__(256)
void bias_fill(const float* __restrict__ b, float4* __restrict__ out) {
    int t = blockIdx.x * 256 + threadIdx.x;
    out[t] = ((const float4*)b)[t & 255];
}

// ---------------------------------------------------------------------------
// gemm_gl2: m97-structure GEMM at 4 BLOCKS/CU (the R9 change).
//
// R8 post-mortem: the 2-phase loop at 2 blocks/CU spends ~1300cy/phase in the
// __syncthreads vmcnt drain (8 waves/CU can't cover it); m97's 36% needed
// 3 blocks/CU (m114: cross-block TLP is what hides the drain).  R9: BK=32
// halves LDS; we REQUEST 40KB dynamic so HW occupancy = floor(160/40) = 4
// blocks/CU exactly (prior session: gload_lds corrupts at >4/CU -- 4 is the
// documented-safe max).  16 waves/CU: one block's drain overlaps three
// others' compute.  Loop skeleton identical to R8 (no asm; R6 lesson).
//
// K-split (ATOMIC=true): grid.z splits K; f32 unsafeAtomicAdd into
// bias-prefilled output (R2-proven).
//
// Staging (BK=32, 64B rows, 4 x 16B slots): thread tid covers LDS bytes
// c*4096 + tid*16 -> row = c*64 + tid/4, slot = tid&3.  gload_lds writes
// linearly, so the swizzle LDS[r][s] = chunk s ^ key2(r),
//   key2(r) = ((r>>1)&3) ^ ((r>>3)&3)
// is applied by pre-swizzling the global source chunk (rule 21); read slot
// = g ^ key2(r), g = ks*2 + khalf in [0,4).  Same 4-lanes-per-slot density
// that measured 0 conflicts at BK=64.
// C/D map (m74/m101): col=lane&31, row=(reg&3)+8*(reg>>2)+4*(lane>>5).
// ---------------------------------------------------------------------------
template<int BM, int BN, int KCH, int KSTR, int GX, int GY,
         bool DO_GELU, bool ATOMIC>
__global__ __launch_bounds__(256, 4)
void gemm_gl2(const unsigned short* __restrict__ A,
              const unsigned short* __restrict__ Bt,
              const float* __restrict__ bias,
              void* __restrict__ Cv,
              int Ncols)
{
    constexpr int BK   = 32;
    constexpr int NT   = KCH / BK;
    constexpr int ASZ  = BM * BK;          // elems
    constexpr int BSZ  = BN * BK;
    constexpr int BUFE = ASZ + BSZ;
    constexpr int ACH  = BM / 64;          // 4KB chunks in A tile
    constexpr int BCH  = BN / 64;
    constexpr int FI   = BM / 64, FJ = BN / 64;

    extern __shared__ unsigned short sh[];   // [2][BUFE] (40KB requested)

    const int tid   = threadIdx.x;
    const int lane  = tid & 63;
    const int wave  = tid >> 6;            // 0..3
    const int m32   = lane & 31;
    const int khalf = lane >> 5;
    const int waveM = (wave >> 1) * (BM / 2);
    const int waveN = (wave & 1) * (BN / 2);
    const int srow  = tid >> 2;            // staging row-within-chunk (0..63)
    const int sslot = tid & 3;             // staging 16B slot

    // XCD-chunked bijective block swizzle over (x,y,z); totals 1024 (%8==0)
    int lin = ((int)blockIdx.z * GY + (int)blockIdx.y) * GX + (int)blockIdx.x;
    const int total = GX * GY * (int)gridDim.z;
    lin = (lin & 7) * (total >> 3) + (lin >> 3);
    const int colBase = (lin % GX) * BN;
    const int rowBase = ((lin / GX) % GY) * BM;
    const int kOff    = (lin / (GX * GY)) * KCH;

#define GL2_STAGE(B_, K0_)                                                    \
    {                                                                         \
        _Pragma("unroll")                                                     \
        for (int c = 0; c < ACH; ++c) {                                       \
            const int r  = c * 64 + srow;                                     \
            const int jg = sslot ^ (((r >> 1) & 3) ^ ((r >> 3) & 3));         \
            const unsigned short* src = A +                                   \
                (size_t)(rowBase + r) * KSTR + (K0_) + jg * 8;                \
            unsigned short* dst = sh + (B_) * BUFE + c * 2048 + wave * 512;   \
            __builtin_amdgcn_global_load_lds(                                 \
                (const __attribute__((address_space(1))) void*)src,           \
                (__attribute__((address_space(3))) void*)dst, 16, 0, 0);      \
        }                                                                     \
        _Pragma("unroll")                                                     \
        for (int c = 0; c < BCH; ++c) {                                       \
            const int r  = c * 64 + srow;                                     \
            const int jg = sslot ^ (((r >> 1) & 3) ^ ((r >> 3) & 3));         \
            const unsigned short* src = Bt +                                  \
                (size_t)(colBase + r) * KSTR + (K0_) + jg * 8;                \
            unsigned short* dst = sh + (B_) * BUFE + ASZ + c * 2048           \
                                  + wave * 512;                               \
            __builtin_amdgcn_global_load_lds(                                 \
                (const __attribute__((address_space(1))) void*)src,           \
                (__attribute__((address_space(3))) void*)dst, 16, 0, 0);      \
        }                                                                     \
    }

    f32x16 acc[FI][FJ] = {};

    // prologue: stage tile 0 into buf 0 (syncthreads drains vmcnt -> landed)
    GL2_STAGE(0, kOff)
    __syncthreads();

    int buf = 0;
    for (int t = 0; t < NT; ++t) {
        if (t + 1 < NT) GL2_STAGE(buf ^ 1, kOff + (t + 1) * BK)

        const unsigned short* Ab = sh + buf * BUFE;
        const unsigned short* Bb = Ab + ASZ;
#pragma unroll
        for (int ks = 0; ks < 2; ++ks) {
            bf16x8 a_f[FI], b_f[FJ];
            const int g = ks * 2 + khalf;
#pragma unroll
            for (int i = 0; i < FI; ++i) {
                const int r = waveM + i * 32 + m32;
                const int key = ((r >> 1) & 3) ^ ((r >> 3) & 3);
                a_f[i] = *(const bf16x8*)&Ab[r * BK + ((g ^ key) << 3)];
            }
#pragma unroll
            for (int j = 0; j < FJ; ++j) {
                const int r = waveN + j * 32 + m32;
                const int key = ((r >> 1) & 3) ^ ((r >> 3) & 3);
                b_f[j] = *(const bf16x8*)&Bb[r * BK + ((g ^ key) << 3)];
            }
#pragma unroll
            for (int i = 0; i < FI; ++i)
#pragma unroll
                for (int j = 0; j < FJ; ++j)
                    acc[i][j] = __builtin_amdgcn_mfma_f32_32x32x16_bf16(
                        a_f[i], b_f[j], acc[i][j], 0, 0, 0);
        }
        __syncthreads();   // drains vmcnt(0): tile t+1 landed; buf reads done
        buf ^= 1;
    }
#undef GL2_STAGE

    // epilogue: col=lane&31, row=(reg&3)+8*(reg>>2)+4*(lane>>5)
#pragma unroll
    for (int i = 0; i < FI; ++i) {
#pragma unroll
        for (int j = 0; j < FJ; ++j) {
            const int col = colBase + waveN + j * 32 + m32;
            const float bv = ATOMIC ? 0.f : bias[col];
#pragma unroll
            for (int reg = 0; reg < 16; ++reg) {
                const int row = rowBase + waveM + i * 32 +
                                (reg & 3) + 8 * (reg >> 2) + 4 * khalf;
                const size_t off = (size_t)row * Ncols + col;
                if (ATOMIC) {
                    unsafeAtomicAdd((float*)Cv + off, acc[i][j][reg]);
                } else {
                    float z = acc[i][j][reg] + bv;
                    if (DO_GELU)
                        z = 0.5f * z * (1.f + erff(z * 0.70710678118654752f));
                    ((unsigned short*)Cv)[off] = f2b(z);
                }
            }
        }
    }
}

// ---------------------------------------------------------------------------
// gemm_pc: R0's producer-consumer GEMM (fallback path; 62us/GEMM proven).
// ---------------------------------------------------------------------------
#define PC_COMPUTE(BUF)                                                       \
    {                                                                         \
        _Pragma("unroll")                                                     \
        for (int ks = 0; ks < 4; ++ks) {                                      \
            bf16x8 a_f[FI], b_f[FJ];                                          \
            _Pragma("unroll")                                                 \
            for (int i = 0; i < FI; ++i) {                                    \
                const int key = (m32 & 7) ^                                   \
                    (((waveM >> 3) + 4 * i + (m32 >> 3)) & 7);                \
                const int slot = ((ks * 2 + khalf) ^ key) * 8;                \
                a_f[i] = *(const bf16x8*)&As[(BUF) * ASZ +                    \
                          (waveM + i * 32 + m32) * BK + slot];                \
            }                                                                 \
            _Pragma("unroll")                                                 \
            for (int j = 0; j < FJ; ++j) {                                    \
                const int key = (m32 & 7) ^                                   \
                    (((waveN >> 3) + 4 * j + (m32 >> 3)) & 7);                \
                const int slot = ((ks * 2 + khalf) ^ key) * 8;                \
                b_f[j] = *(const bf16x8*)&Bs[(BUF) * BSZ +                    \
                          (waveN + j * 32 + m32) * BK + slot];                \
            }                                                                 \
            _Pragma("unroll")                                                 \
            for (int i = 0; i < FI; ++i)                                      \
                _Pragma("unroll")                                             \
                for (int j = 0; j < FJ; ++j)                                  \
                    acc[i][j] = __builtin_amdgcn_mfma_f32_32x32x16_bf16(      \
                        a_f[i], b_f[j], acc[i][j], 0, 0, 0);                  \
        }                                                                     \
    }

template<int BM, int BN, int KTOT, bool DO_GELU, bool A_F32, bool C_F32>
__global__ __launch_bounds__(512, 4)
void gemm_pc(const void* __restrict__ Av,
             const unsigned short* __restrict__ Bt,
             const float* __restrict__ bias,
             void* __restrict__ Cv,
             int Ncols) {
    constexpr int BK  = 64;
    constexpr int CA  = BM / 8;
    constexpr int CB  = BN / 8;
    constexpr int PA  = CA / 4;
    constexpr int PB  = CB / 4;
    constexpr int FI  = BM / 64;
    constexpr int FJ  = BN / 64;
    constexpr int ASZ = BM * BK;
    constexpr int BSZ = BN * BK;
    __shared__ unsigned short As[2 * ASZ];
    __shared__ unsigned short Bs[2 * BSZ];

    const int tid  = threadIdx.x;
    const int lane = tid & 63;
    const int wave = tid >> 6;
    const int rowBase = blockIdx.y * BM;
    const int colBase = blockIdx.x * BN;

    const int lr    = lane >> 3;
    const int jj    = lane & 7;
    const int m32   = lane & 31;
    const int khalf = lane >> 5;

    if (wave >= 4) {
        const int pw = wave - 4;
#pragma unroll
        for (int it = 0; it < PA; ++it) {
            const int c  = pw * PA + it;
            const int jg = jj ^ lr ^ (c & 7);
            const size_t aoff = (size_t)(rowBase + c * 8 + lr) * KTOT + jg * 8;
            int4 v;
            if (A_F32) {
                const float* ga = (const float*)Av + aoff;
                float4 f0 = *(const float4*)ga;
                float4 f1 = *(const float4*)(ga + 4);
                v.x = (uint32_t)f2b(f0.x) | ((uint32_t)f2b(f0.y) << 16);
                v.y = (uint32_t)f2b(f0.z) | ((uint32_t)f2b(f0.w) << 16);
                v.z = (uint32_t)f2b(f1.x) | ((uint32_t)f2b(f1.y) << 16);
                v.w = (uint32_t)f2b(f1.z) | ((uint32_t)f2b(f1.w) << 16);
            } else {
                v = *(const int4*)((const unsigned short*)Av + aoff);
            }
            *(int4*)&As[c * 512 + lane * 8] = v;
        }
#pragma unroll
        for (int it = 0; it < PB; ++it) {
            const int c  = pw * PB + it;
            const int jg = jj ^ lr ^ (c & 7);
            *(int4*)&Bs[c * 512 + lane * 8] =
                *(const int4*)(Bt + (size_t)(colBase + c * 8 + lr) * KTOT + jg * 8);
        }
        __syncthreads();

        int buf = 1;
        for (int k0 = BK; k0 < KTOT; k0 += BK) {
            int4 aR[PA], bR[PB];
#pragma unroll
            for (int it = 0; it < PA; ++it) {
                const int c  = pw * PA + it;
                const int jg = jj ^ lr ^ (c & 7);
                const size_t aoff = (size_t)(rowBase + c * 8 + lr) * KTOT + k0 + jg * 8;
                if (A_F32) {
                    const float* ga = (const float*)Av + aoff;
                    float4 f0 = *(const float4*)ga;
                    float4 f1 = *(const float4*)(ga + 4);
                    int4 v;
                    v.x = (uint32_t)f2b(f0.x) | ((uint32_t)f2b(f0.y) << 16);
                    v.y = (uint32_t)f2b(f0.z) | ((uint32_t)f2b(f0.w) << 16);
                    v.z = (uint32_t)f2b(f1.x) | ((uint32_t)f2b(f1.y) << 16);
                    v.w = (uint32_t)f2b(f1.z) | ((uint32_t)f2b(f1.w) << 16);
                    aR[it] = v;
                } else {
                    aR[it] = *(const int4*)((const unsigned short*)Av + aoff);
                }
            }
#pragma unroll
            for (int it = 0; it < PB; ++it) {
                const int c  = pw * PB + it;
                const int jg = jj ^ lr ^ (c & 7);
                bR[it] = *(const int4*)(Bt + (size_t)(colBase + c * 8 + lr) * KTOT + k0 + jg * 8);
            }
#pragma unroll
            for (int it = 0; it < PA; ++it) {
                const int c = pw * PA + it;
                *(int4*)&As[buf * ASZ + c * 512 + lane * 8] = aR[it];
            }
#pragma unroll
            for (int it = 0; it < PB; ++it) {
                const int c = pw * PB + it;
                *(int4*)&Bs[buf * BSZ + c * 512 + lane * 8] = bR[it];
            }
            __syncthreads();
            buf ^= 1;
        }
    } else {
        const int waveM = (wave >> 1) * (BM / 2);
        const int waveN = (wave & 1) * (BN / 2);
        f32x16 acc[FI][FJ] = {};

        __syncthreads();

        int cur = 0;
        for (int k0 = BK; k0 < KTOT; k0 += BK) {
            PC_COMPUTE(cur)
            __syncthreads();
            cur ^= 1;
        }
        PC_COMPUTE(cur)

#pragma unroll
        for (int i = 0; i < FI; ++i) {
#pragma unroll
            for (int j = 0; j < FJ; ++j) {
                const int col = colBase + waveN + j * 32 + m32;
                const float bv = bias[col];
#pragma unroll
                for (int reg = 0; reg < 16; ++reg) {
                    const int row = rowBase + waveM + i * 32 +
                                    (reg & 3) + 8 * (reg >> 2) + 4 * khalf;
                    float z = acc[i][j][reg] + bv;
                    if (DO_GELU)
                        z = 0.5f * z * (1.f + erff(z * 0.70710678118654752f));
                    const size_t off = (size_t)row * Ncols + col;
                    if (C_F32) ((float*)Cv)[off] = z;
                    else       ((unsigned short*)Cv)[off] = f2b(z);
                }
            }
        }
    }
}

// ---------------------------------------------------------------------------
extern "C" void kernel_launch(void* const* d_in, const int* in_sizes, int n_in,
                              void* d_out, int out_size, void* d_ws, size_t ws_size,
                              hipStream_t stream) {
    const float* x      = (const float*)d_in[0];   // [4096,1024] fp32
    const float* fc1_c0 = (const float*)d_in[1];
    const float* fc1_c1 = (const float*)d_in[2];
    const float* fc1_c2 = (const float*)d_in[3];
    const float* fc1_b  = (const float*)d_in[4];
    const float* fc2_c0 = (const float*)d_in[5];
    const float* fc2_c1 = (const float*)d_in[6];
    const float* fc2_c2 = (const float*)d_in[7];
    const float* fc2_b  = (const float*)d_in[8];

    // d_out (16 MB f32) as pre-GEMM2 scratch:
    //   T1 [0,2M), T2 [2,4M), xb bf16 [4,12M).  Verified safe R5-R8.
    //   bias_fill (AFTER GEMM1) overwrites scratch, then GEMM2 atomics += .
    float* T1 = (float*)d_out;
    float* T2 = (float*)d_out + 524288;
    unsigned short* xb = (unsigned short*)((char*)d_out + (4u << 20));

    char* ws = (char*)d_ws;
    const bool big = ws_size >= (48ull << 20);

    // Request 40KB dynamic LDS (use 32/24KB) -> occupancy capped at exactly
    // 4 blocks/CU (160/40), the documented-safe gload_lds maximum.
    constexpr int DLDS = 40 << 10;

    // K0: T1 + T2 + cvt(x->xb), fused (2048+2048+2048 blocks)
    prep_stage1<<<6144, 256, 0, stream>>>(fc1_c1, fc1_c2, T1,
                                          fc2_c1, fc2_c2, T2, x, xb);

    if (big) {
        // ws: W1 [0,8M), W2 [8,16M), h bf16 [16,48M)
        unsigned short* W1 = (unsigned short*)ws;
        unsigned short* W2 = (unsigned short*)(ws + (8u << 20));
        unsigned short* h  = (unsigned short*)(ws + (16u << 20));

        // K1: both weight matrices (2048 + 1024 blocks)
        build_W_both<<<3072, 256, 0, stream>>>(fc1_c0, T1, W1,
                                               fc2_c0, T2, W2);
        // K2: GEMM1 [4096,1024]x[1024,4096]^T + bias + GELU -> h (bf16)
        //     128x128, BK=32, grid 32x32 = 1024 blocks = 4/CU, one round.
        gemm_gl2<128, 128, 1024, 1024, 32, 32, true, false>
            <<<dim3(32, 32, 1), 256, DLDS, stream>>>(xb, W1, fc1_b, h, 4096);
        // K3: prefill d_out rows with bias (scratch is dead now)
        bias_fill<<<4096, 256, 0, stream>>>(fc2_b, (float4*)d_out);
        // K4: GEMM2 [4096,4096]x[4096,1024]^T, K-split 2, atomic += d_out
        //     128x64, BK=32, grid 16x32x2 = 1024 blocks = 4/CU, one round.
        gemm_gl2<128, 64, 2048, 4096, 16, 32, false, true>
            <<<dim3(16, 32, 2), 256, DLDS, stream>>>(h, W2, fc2_b, d_out, 1024);
    } else {
        // Fallback (ws >= 40 MB): W [0,8M) reused per layer, h [8,40M).
        unsigned short* W = (unsigned short*)ws;
        unsigned short* h = (unsigned short*)(ws + (8u << 20));

        build_W<8, 16, 8, 16, 16, 16><<<2048, 256, 0, stream>>>(fc1_c0, T1, W);
        gemm_pc<128, 128, 1024, true, false, false>
            <<<dim3(32, 32), 512, 0, stream>>>(xb, W, fc1_b, h, 4096);
        build_W<16, 16, 16, 8, 16, 8><<<1024, 256, 0, stream>>>(fc2_c0, T2, W);
        gemm_pc<128, 64, 4096, false, false, true>
            <<<dim3(16, 32), 512, 0, stream>>>(h, W, fc2_b, d_out, 1024);
    }
}

// Round 10
// 235.729 us; speedup vs baseline: 1.0555x; 1.0555x over previous
//
#include <hip/hip_runtime.h>
#include <stdint.h>

// ---------- bf16 helpers (storage = unsigned short) ----------
__device__ __forceinline__ float b2f(unsigned short u) {
    union { uint32_t i; float f; } v; v.i = ((uint32_t)u) << 16; return v.f;
}
__device__ __forceinline__ unsigned short f2b(float f) {
    union { float f; uint32_t i; } v; v.f = f;
    uint32_t r = v.i + 0x7fffu + ((v.i >> 16) & 1u);   // RNE
    return (unsigned short)(r >> 16);
}

typedef __bf16 bf16x8 __attribute__((ext_vector_type(8)));
typedef float  f32x16 __attribute__((ext_vector_type(16)));

// ---------------------------------------------------------------------------
// build_T body: T[rm=(r1*16+n2)*16+m2][n3][m3] = sum_r2 c1[rm][r2]*c2[...]
// 524288 elems per layer (2048 blocks x 256; R3 lesson: never shrink).
// ---------------------------------------------------------------------------
template<int N3, int M3>
__device__ __forceinline__ void build_T_body(int e,
                                             const float* __restrict__ c1,
                                             const float* __restrict__ c2,
                                             float* __restrict__ T) {
    int m3 = e % M3;
    int t  = e / M3;
    int n3 = t % N3;
    int rm = t / N3;
    float s = 0.f;
#pragma unroll
    for (int r2 = 0; r2 < 16; ++r2)
        s += c1[rm * 16 + r2] * c2[(r2 * N3 + n3) * M3 + m3];
    T[e] = s;
}

// Fused stage-1: blocks [0,2048) -> T1, [2048,4096) -> T2,
// [4096,6144) -> cvt x (f32) -> xb (bf16).  Verified R5-R9.
__global__ __launch_bounds__(256)
void prep_stage1(const float* __restrict__ c11, const float* __restrict__ c12,
                 float* __restrict__ T1,
                 const float* __restrict__ c21, const float* __restrict__ c22,
                 float* __restrict__ T2,
                 const float* __restrict__ x, unsigned short* __restrict__ xb) {
    const int b = blockIdx.x;
    if (b < 2048) {
        build_T_body<8, 16>(b * 256 + threadIdx.x, c11, c12, T1);
    } else if (b < 4096) {
        build_T_body<16, 8>((b - 2048) * 256 + threadIdx.x, c21, c22, T2);
    } else {
        const int t = (b - 4096) * 256 + threadIdx.x;
        const float4* p = (const float4*)(x + (size_t)t * 8);
        float4 f0 = p[0], f1 = p[1];
        int4 o;
        o.x = (uint32_t)f2b(f0.x) | ((uint32_t)f2b(f0.y) << 16);
        o.y = (uint32_t)f2b(f0.z) | ((uint32_t)f2b(f0.w) << 16);
        o.z = (uint32_t)f2b(f1.x) | ((uint32_t)f2b(f1.y) << 16);
        o.w = (uint32_t)f2b(f1.z) | ((uint32_t)f2b(f1.w) << 16);
        ((int4*)xb)[t] = o;
    }
}

// ---------------------------------------------------------------------------
// build_W body: thread t = (((n1*M1+m1)*N2+n2)*M2+m2)*M3+m3.
// W[outRow=(m1*M2+m2)*M3+m3][K] (B^T layout, bf16), K = N1*N2*N3.
// ---------------------------------------------------------------------------
template<int N1, int N2, int N3, int M1, int M2, int M3>
__device__ __forceinline__ void build_W_body(int t,
                                             const float* __restrict__ c0,
                                             const float* __restrict__ T,
                                             unsigned short* __restrict__ W) {
    constexpr int K = N1 * N2 * N3;
    int m3 = t % M3;
    int m2 = (t / M3) % M2;
    int n2 = (t / (M3 * M2)) % N2;
    int m1 = (t / (M3 * M2 * N2)) % M1;
    int n1 =  t / (M3 * M2 * N2 * M1);

    float c0r[16];
    const float4* c0p = (const float4*)(c0 + (n1 * M1 + m1) * 16);
#pragma unroll
    for (int i = 0; i < 4; ++i) ((float4*)c0r)[i] = c0p[i];

    float acc[N3] = {};
#pragma unroll
    for (int r1 = 0; r1 < 16; ++r1) {
        const float* Tp = T + (size_t)(((r1 * 16 + n2) * 16 + m2) * N3) * M3 + m3;
#pragma unroll
        for (int n3 = 0; n3 < N3; ++n3)
            acc[n3] += c0r[r1] * Tp[n3 * M3];
    }

    unsigned short ob[N3];
#pragma unroll
    for (int n3 = 0; n3 < N3; ++n3) ob[n3] = f2b(acc[n3]);

    unsigned short* dst = W + (size_t)((m1 * M2 + m2) * M3 + m3) * K
                            + (n1 * N2 + n2) * N3;
#pragma unroll
    for (int c = 0; c < N3 / 8; ++c)
        ((int4*)dst)[c] = ((const int4*)ob)[c];
}

// Fused: blocks [0,2048) -> W1, [2048,3072) -> W2.  Verified R5-R9.
__global__ __launch_bounds__(256)
void build_W_both(const float* __restrict__ c10, const float* __restrict__ T1,
                  unsigned short* __restrict__ W1,
                  const float* __restrict__ c20, const float* __restrict__ T2,
                  unsigned short* __restrict__ W2) {
    const int b = blockIdx.x;
    if (b < 2048)
        build_W_body<8, 16, 8, 16, 16, 16>(b * 256 + threadIdx.x, c10, T1, W1);
    else
        build_W_body<16, 16, 16, 8, 16, 8>((b - 2048) * 256 + threadIdx.x, c20, T2, W2);
}

// Standalone (small-workspace fallback path only).
template<int N1, int N2, int N3, int M1, int M2, int M3>
__global__ __launch_bounds__(256)
void build_W(const float* __restrict__ c0, const float* __restrict__ T,
             unsigned short* __restrict__ W) {
    build_W_body<N1, N2, N3, M1, M2, M3>(blockIdx.x * 256 + threadIdx.x, c0, T, W);
}

// ---------------------------------------------------------------------------
// bias_fill: out[r][c] = bias[c]  (f32).  Runs AFTER GEMM1 (scratch dead).
// ---------------------------------------------------------------------------
__global__ __launch_bounds__(256)
void bias_fill(const float* __restrict__ b, float4* __restrict__ out) {
    int t = blockIdx.x * 256 + threadIdx.x;
    out[t] = ((const float4*)b)[t & 255];
}

// ---------------------------------------------------------------------------
// gemm_sb: SINGLE-buffered BK=64 m97-style 2-barrier loop at 4 BLOCKS/CU.
//
// R9 lesson: BK=32 swizzle conflicts (6.3M cyc, 13% tax) -- rows must be
// 128B (full 32-bank sweep) for the proven-0-conflict key.  R10: keep BK=64
// geometry, drop the double buffer: 32KB used, 40KB REQUESTED -> exactly
// floor(160/40) = 4 blocks/CU (documented-safe gload_lds max; R9 ran 4/CU
// correctly).  16 waves/CU: per SIMD, 4 waves from 4 INDEPENDENT blocks ->
// per tile each SIMD owes 4 x 541cy of MFMA vs ~1500cy block cycle; the
// matrix pipe is oversubscribed, so cross-block TLP (m114) covers each
// block's in-path vmcnt drain.  __launch_bounds__(256,4) caps VGPR <= 128.
//
// K-step: STAGE(t) -> __syncthreads (vm drain: tile landed) -> COMPUTE ->
// __syncthreads (reads done before next stage overwrite).  No asm (R6).
//
// Staging/read/epilogue are R8's verified code verbatim (pre-swizzled
// gload_lds source; read slot = g ^ (r&7) ^ ((r>>3)&7); measured 0
// conflicts).  ATOMIC path (GEMM2 K-split=2): f32 unsafeAtomicAdd into
// bias-prefilled d_out (R9-verified ordering).
// C/D map (m74/m101): col=lane&31, row=(reg&3)+8*(reg>>2)+4*(lane>>5).
// ---------------------------------------------------------------------------
template<int BM, int BN, int KCH, int KSTR, int GX, int GY,
         bool DO_GELU, bool ATOMIC>
__global__ __launch_bounds__(256, 4)
void gemm_sb(const unsigned short* __restrict__ A,
             const unsigned short* __restrict__ Bt,
             const float* __restrict__ bias,
             void* __restrict__ Cv,
             int Ncols)
{
    constexpr int BK  = 64;
    constexpr int NT  = KCH / BK;
    constexpr int ASZ = BM * BK;           // elems
    constexpr int ACH = BM / 32;           // 4KB chunks (32 rows x 128B)
    constexpr int BCH = BN / 32;
    constexpr int FI  = BM / 64, FJ = BN / 64;

    extern __shared__ unsigned short sh[];   // [ASZ + BSZ] (40KB requested)

    const int tid   = threadIdx.x;
    const int lane  = tid & 63;
    const int wave  = tid >> 6;            // 0..3
    const int m32   = lane & 31;
    const int khalf = lane >> 5;
    const int waveM = (wave >> 1) * (BM / 2);
    const int waveN = (wave & 1) * (BN / 2);
    const int srow  = tid >> 3;            // staging row-within-chunk (0..31)
    const int sslot = tid & 7;             // staging 16B slot

    // XCD-chunked bijective block swizzle over (x,y,z); totals 1024 (%8==0)
    int lin = ((int)blockIdx.z * GY + (int)blockIdx.y) * GX + (int)blockIdx.x;
    const int total = GX * GY * (int)gridDim.z;
    lin = (lin & 7) * (total >> 3) + (lin >> 3);
    const int colBase = (lin % GX) * BN;
    const int rowBase = ((lin / GX) % GY) * BM;
    const int kOff    = (lin / (GX * GY)) * KCH;

#define SB_STAGE(K0_)                                                         \
    {                                                                         \
        _Pragma("unroll")                                                     \
        for (int c = 0; c < ACH; ++c) {                                       \
            const int r  = c * 32 + srow;                                     \
            const int jg = sslot ^ (r & 7) ^ ((r >> 3) & 7);                  \
            const unsigned short* src = A +                                   \
                (size_t)(rowBase + r) * KSTR + (K0_) + jg * 8;                \
            unsigned short* dst = sh + c * 2048 + wave * 512;                 \
            __builtin_amdgcn_global_load_lds(                                 \
                (const __attribute__((address_space(1))) void*)src,           \
                (__attribute__((address_space(3))) void*)dst, 16, 0, 0);      \
        }                                                                     \
        _Pragma("unroll")                                                     \
        for (int c = 0; c < BCH; ++c) {                                       \
            const int r  = c * 32 + srow;                                     \
            const int jg = sslot ^ (r & 7) ^ ((r >> 3) & 7);                  \
            const unsigned short* src = Bt +                                  \
                (size_t)(colBase + r) * KSTR + (K0_) + jg * 8;                \
            unsigned short* dst = sh + ASZ + c * 2048 + wave * 512;           \
            __builtin_amdgcn_global_load_lds(                                 \
                (const __attribute__((address_space(1))) void*)src,           \
                (__attribute__((address_space(3))) void*)dst, 16, 0, 0);      \
        }                                                                     \
    }

    f32x16 acc[FI][FJ] = {};

    for (int t = 0; t < NT; ++t) {
        SB_STAGE(kOff + t * BK)
        __syncthreads();                   // vm drain: tile t landed

        const unsigned short* Ab = sh;
        const unsigned short* Bb = sh + ASZ;
#pragma unroll
        for (int ks = 0; ks < 4; ++ks) {
            bf16x8 a_f[FI], b_f[FJ];
            const int g = ks * 2 + khalf;
#pragma unroll
            for (int i = 0; i < FI; ++i) {
                const int r = waveM + i * 32 + m32;
                const int key = (r & 7) ^ ((r >> 3) & 7);
                a_f[i] = *(const bf16x8*)&Ab[r * BK + ((g ^ key) << 3)];
            }
#pragma unroll
            for (int j = 0; j < FJ; ++j) {
                const int r = waveN + j * 32 + m32;
                const int key = (r & 7) ^ ((r >> 3) & 7);
                b_f[j] = *(const bf16x8*)&Bb[r * BK + ((g ^ key) << 3)];
            }
#pragma unroll
            for (int i = 0; i < FI; ++i)
#pragma unroll
                for (int j = 0; j < FJ; ++j)
                    acc[i][j] = __builtin_amdgcn_mfma_f32_32x32x16_bf16(
                        a_f[i], b_f[j], acc[i][j], 0, 0, 0);
        }
        if (t + 1 < NT) __syncthreads();   // reads done before next stage
    }
#undef SB_STAGE

    // epilogue: col=lane&31, row=(reg&3)+8*(reg>>2)+4*(lane>>5)
#pragma unroll
    for (int i = 0; i < FI; ++i) {
#pragma unroll
        for (int j = 0; j < FJ; ++j) {
            const int col = colBase + waveN + j * 32 + m32;
            const float bv = ATOMIC ? 0.f : bias[col];
#pragma unroll
            for (int reg = 0; reg < 16; ++reg) {
                const int row = rowBase + waveM + i * 32 +
                                (reg & 3) + 8 * (reg >> 2) + 4 * khalf;
                const size_t off = (size_t)row * Ncols + col;
                if (ATOMIC) {
                    unsafeAtomicAdd((float*)Cv + off, acc[i][j][reg]);
                } else {
                    float z = acc[i][j][reg] + bv;
                    if (DO_GELU)
                        z = 0.5f * z * (1.f + erff(z * 0.70710678118654752f));
                    ((unsigned short*)Cv)[off] = f2b(z);
                }
            }
        }
    }
}

// ---------------------------------------------------------------------------
// gemm_pc: R0's producer-consumer GEMM (fallback path; 62us/GEMM proven).
// ---------------------------------------------------------------------------
#define PC_COMPUTE(BUF)                                                       \
    {                                                                         \
        _Pragma("unroll")                                                     \
        for (int ks = 0; ks < 4; ++ks) {                                      \
            bf16x8 a_f[FI], b_f[FJ];                                          \
            _Pragma("unroll")                                                 \
            for (int i = 0; i < FI; ++i) {                                    \
                const int key = (m32 & 7) ^                                   \
                    (((waveM >> 3) + 4 * i + (m32 >> 3)) & 7);                \
                const int slot = ((ks * 2 + khalf) ^ key) * 8;                \
                a_f[i] = *(const bf16x8*)&As[(BUF) * ASZ +                    \
                          (waveM + i * 32 + m32) * BK + slot];                \
            }                                                                 \
            _Pragma("unroll")                                                 \
            for (int j = 0; j < FJ; ++j) {                                    \
                const int key = (m32 & 7) ^                                   \
                    (((waveN >> 3) + 4 * j + (m32 >> 3)) & 7);                \
                const int slot = ((ks * 2 + khalf) ^ key) * 8;                \
                b_f[j] = *(const bf16x8*)&Bs[(BUF) * BSZ +                    \
                          (waveN + j * 32 + m32) * BK + slot];                \
            }                                                                 \
            _Pragma("unroll")                                                 \
            for (int i = 0; i < FI; ++i)                                      \
                _Pragma("unroll")                                             \
                for (int j = 0; j < FJ; ++j)                                  \
                    acc[i][j] = __builtin_amdgcn_mfma_f32_32x32x16_bf16(      \
                        a_f[i], b_f[j], acc[i][j], 0, 0, 0);                  \
        }                                                                     \
    }

template<int BM, int BN, int KTOT, bool DO_GELU, bool A_F32, bool C_F32>
__global__ __launch_bounds__(512, 4)
void gemm_pc(const void* __restrict__ Av,
             const unsigned short* __restrict__ Bt,
             const float* __restrict__ bias,
             void* __restrict__ Cv,
             int Ncols) {
    constexpr int BK  = 64;
    constexpr int CA  = BM / 8;
    constexpr int CB  = BN / 8;
    constexpr int PA  = CA / 4;
    constexpr int PB  = CB / 4;
    constexpr int FI  = BM / 64;
    constexpr int FJ  = BN / 64;
    constexpr int ASZ = BM * BK;
    constexpr int BSZ = BN * BK;
    __shared__ unsigned short As[2 * ASZ];
    __shared__ unsigned short Bs[2 * BSZ];

    const int tid  = threadIdx.x;
    const int lane = tid & 63;
    const int wave = tid >> 6;
    const int rowBase = blockIdx.y * BM;
    const int colBase = blockIdx.x * BN;

    const int lr    = lane >> 3;
    const int jj    = lane & 7;
    const int m32   = lane & 31;
    const int khalf = lane >> 5;

    if (wave >= 4) {
        const int pw = wave - 4;
#pragma unroll
        for (int it = 0; it < PA; ++it) {
            const int c  = pw * PA + it;
            const int jg = jj ^ lr ^ (c & 7);
            const size_t aoff = (size_t)(rowBase + c * 8 + lr) * KTOT + jg * 8;
            int4 v;
            if (A_F32) {
                const float* ga = (const float*)Av + aoff;
                float4 f0 = *(const float4*)ga;
                float4 f1 = *(const float4*)(ga + 4);
                v.x = (uint32_t)f2b(f0.x) | ((uint32_t)f2b(f0.y) << 16);
                v.y = (uint32_t)f2b(f0.z) | ((uint32_t)f2b(f0.w) << 16);
                v.z = (uint32_t)f2b(f1.x) | ((uint32_t)f2b(f1.y) << 16);
                v.w = (uint32_t)f2b(f1.z) | ((uint32_t)f2b(f1.w) << 16);
            } else {
                v = *(const int4*)((const unsigned short*)Av + aoff);
            }
            *(int4*)&As[c * 512 + lane * 8] = v;
        }
#pragma unroll
        for (int it = 0; it < PB; ++it) {
            const int c  = pw * PB + it;
            const int jg = jj ^ lr ^ (c & 7);
            *(int4*)&Bs[c * 512 + lane * 8] =
                *(const int4*)(Bt + (size_t)(colBase + c * 8 + lr) * KTOT + jg * 8);
        }
        __syncthreads();

        int buf = 1;
        for (int k0 = BK; k0 < KTOT; k0 += BK) {
            int4 aR[PA], bR[PB];
#pragma unroll
            for (int it = 0; it < PA; ++it) {
                const int c  = pw * PA + it;
                const int jg = jj ^ lr ^ (c & 7);
                const size_t aoff = (size_t)(rowBase + c * 8 + lr) * KTOT + k0 + jg * 8;
                if (A_F32) {
                    const float* ga = (const float*)Av + aoff;
                    float4 f0 = *(const float4*)ga;
                    float4 f1 = *(const float4*)(ga + 4);
                    int4 v;
                    v.x = (uint32_t)f2b(f0.x) | ((uint32_t)f2b(f0.y) << 16);
                    v.y = (uint32_t)f2b(f0.z) | ((uint32_t)f2b(f0.w) << 16);
                    v.z = (uint32_t)f2b(f1.x) | ((uint32_t)f2b(f1.y) << 16);
                    v.w = (uint32_t)f2b(f1.z) | ((uint32_t)f2b(f1.w) << 16);
                    aR[it] = v;
                } else {
                    aR[it] = *(const int4*)((const unsigned short*)Av + aoff);
                }
            }
#pragma unroll
            for (int it = 0; it < PB; ++it) {
                const int c  = pw * PB + it;
                const int jg = jj ^ lr ^ (c & 7);
                bR[it] = *(const int4*)(Bt + (size_t)(colBase + c * 8 + lr) * KTOT + k0 + jg * 8);
            }
#pragma unroll
            for (int it = 0; it < PA; ++it) {
                const int c = pw * PA + it;
                *(int4*)&As[buf * ASZ + c * 512 + lane * 8] = aR[it];
            }
#pragma unroll
            for (int it = 0; it < PB; ++it) {
                const int c = pw * PB + it;
                *(int4*)&Bs[buf * BSZ + c * 512 + lane * 8] = bR[it];
            }
            __syncthreads();
            buf ^= 1;
        }
    } else {
        const int waveM = (wave >> 1) * (BM / 2);
        const int waveN = (wave & 1) * (BN / 2);
        f32x16 acc[FI][FJ] = {};

        __syncthreads();

        int cur = 0;
        for (int k0 = BK; k0 < KTOT; k0 += BK) {
            PC_COMPUTE(cur)
            __syncthreads();
            cur ^= 1;
        }
        PC_COMPUTE(cur)

#pragma unroll
        for (int i = 0; i < FI; ++i) {
#pragma unroll
            for (int j = 0; j < FJ; ++j) {
                const int col = colBase + waveN + j * 32 + m32;
                const float bv = bias[col];
#pragma unroll
                for (int reg = 0; reg < 16; ++reg) {
                    const int row = rowBase + waveM + i * 32 +
                                    (reg & 3) + 8 * (reg >> 2) + 4 * khalf;
                    float z = acc[i][j][reg] + bv;
                    if (DO_GELU)
                        z = 0.5f * z * (1.f + erff(z * 0.70710678118654752f));
                    const size_t off = (size_t)row * Ncols + col;
                    if (C_F32) ((float*)Cv)[off] = z;
                    else       ((unsigned short*)Cv)[off] = f2b(z);
                }
            }
        }
    }
}

// ---------------------------------------------------------------------------
extern "C" void kernel_launch(void* const* d_in, const int* in_sizes, int n_in,
                              void* d_out, int out_size, void* d_ws, size_t ws_size,
                              hipStream_t stream) {
    const float* x      = (const float*)d_in[0];   // [4096,1024] fp32
    const float* fc1_c0 = (const float*)d_in[1];
    const float* fc1_c1 = (const float*)d_in[2];
    const float* fc1_c2 = (const float*)d_in[3];
    const float* fc1_b  = (const float*)d_in[4];
    const float* fc2_c0 = (const float*)d_in[5];
    const float* fc2_c1 = (const float*)d_in[6];
    const float* fc2_c2 = (const float*)d_in[7];
    const float* fc2_b  = (const float*)d_in[8];

    // d_out (16 MB f32) as pre-GEMM2 scratch:
    //   T1 [0,2M), T2 [2,4M), xb bf16 [4,12M).  Verified safe R5-R9.
    //   bias_fill (AFTER GEMM1) overwrites scratch, then GEMM2 atomics +=.
    float* T1 = (float*)d_out;
    float* T2 = (float*)d_out + 524288;
    unsigned short* xb = (unsigned short*)((char*)d_out + (4u << 20));

    char* ws = (char*)d_ws;
    const bool big = ws_size >= (48ull << 20);

    // Request 40KB dynamic LDS (use 32/24KB) -> occupancy = floor(160/40)
    // = exactly 4 blocks/CU, the documented-safe gload_lds maximum.
    constexpr int DLDS = 40 << 10;

    // K0: T1 + T2 + cvt(x->xb), fused (2048+2048+2048 blocks)
    prep_stage1<<<6144, 256, 0, stream>>>(fc1_c1, fc1_c2, T1,
                                          fc2_c1, fc2_c2, T2, x, xb);

    if (big) {
        // ws: W1 [0,8M), W2 [8,16M), h bf16 [16,48M)
        unsigned short* W1 = (unsigned short*)ws;
        unsigned short* W2 = (unsigned short*)(ws + (8u << 20));
        unsigned short* h  = (unsigned short*)(ws + (16u << 20));

        // K1: both weight matrices (2048 + 1024 blocks)
        build_W_both<<<3072, 256, 0, stream>>>(fc1_c0, T1, W1,
                                               fc2_c0, T2, W2);
        // K2: GEMM1 [4096,1024]x[1024,4096]^T + bias + GELU -> h (bf16)
        //     128x128, BK=64 single-buffer, grid 32x32 = 1024 = 4/CU.
        gemm_sb<128, 128, 1024, 1024, 32, 32, true, false>
            <<<dim3(32, 32, 1), 256, DLDS, stream>>>(xb, W1, fc1_b, h, 4096);
        // K3: prefill d_out rows with bias (scratch is dead now)
        bias_fill<<<4096, 256, 0, stream>>>(fc2_b, (float4*)d_out);
        // K4: GEMM2 [4096,4096]x[4096,1024]^T, K-split 2, atomic += d_out
        //     128x64, BK=64 single-buffer, grid 16x32x2 = 1024 = 4/CU.
        gemm_sb<128, 64, 2048, 4096, 16, 32, false, true>
            <<<dim3(16, 32, 2), 256, DLDS, stream>>>(h, W2, fc2_b, d_out, 1024);
    } else {
        // Fallback (ws >= 40 MB): W [0,8M) reused per layer, h [8,40M).
        unsigned short* W = (unsigned short*)ws;
        unsigned short* h = (unsigned short*)(ws + (8u << 20));

        build_W<8, 16, 8, 16, 16, 16><<<2048, 256, 0, stream>>>(fc1_c0, T1, W);
        gemm_pc<128, 128, 1024, true, false, false>
            <<<dim3(32, 32), 512, 0, stream>>>(xb, W, fc1_b, h, 4096);
        build_W<16, 16, 16, 8, 16, 8><<<1024, 256, 0, stream>>>(fc2_c0, T2, W);
        gemm_pc<128, 64, 4096, false, false, true>
            <<<dim3(16, 32), 512, 0, stream>>>(h, W, fc2_b, d_out, 1024);
    }
}

// Round 11
// 211.678 us; speedup vs baseline: 1.1755x; 1.1136x over previous
//
#include <hip/hip_runtime.h>
#include <stdint.h>

// ---------- bf16 helpers (storage = unsigned short) ----------
__device__ __forceinline__ float b2f(unsigned short u) {
    union { uint32_t i; float f; } v; v.i = ((uint32_t)u) << 16; return v.f;
}
__device__ __forceinline__ unsigned short f2b(float f) {
    union { float f; uint32_t i; } v; v.f = f;
    uint32_t r = v.i + 0x7fffu + ((v.i >> 16) & 1u);   // RNE
    return (unsigned short)(r >> 16);
}

typedef __bf16 bf16x8 __attribute__((ext_vector_type(8)));
typedef float  f32x16 __attribute__((ext_vector_type(16)));

// ---------------------------------------------------------------------------
// build_W_fused: one block owns (n2,m2); computes its T-slice S[r1][n3][m3]
// in LDS (16 x N3 x M3 = 2048 f32 = 8KB for both layers), then the W rows.
// Algebra identical to the verified build_T + build_W chain:
//   S[r1][n3][m3] = sum_r2 c1[((r1*N2+n2)*M2+m2)*16+r2] * c2[(r2*N3+n3)*M3+m3]
//   W[(m1*M2+m2)*M3+m3][(n1*N2+n2)*N3 + n3] = sum_r1 c0[(n1*M1+m1)*16+r1]*S[..]
// S-reads in step 2 broadcast across lanes (m1,n1 don't index S) -> no
// conflicts.  Eliminates the T round-trip through global memory.
// ---------------------------------------------------------------------------
template<int N1, int N2, int N3, int M1, int M2, int M3>
__device__ __forceinline__ void build_W_fused(int blk,
                                              const float* __restrict__ c0,
                                              const float* __restrict__ c1,
                                              const float* __restrict__ c2,
                                              unsigned short* __restrict__ W,
                                              float* __restrict__ S) {
    constexpr int K = N1 * N2 * N3;
    const int n2 = blk / M2;
    const int m2 = blk % M2;

    // step 1: T-slice into LDS
    for (int e = threadIdx.x; e < 16 * N3 * M3; e += 256) {
        const int m3 = e % M3;
        const int n3 = (e / M3) % N3;
        const int r1 = e / (M3 * N3);
        const float* c1p = c1 + ((r1 * N2 + n2) * M2 + m2) * 16;
        float s = 0.f;
#pragma unroll
        for (int r2 = 0; r2 < 16; ++r2)
            s += c1p[r2] * c2[(r2 * N3 + n3) * M3 + m3];
        S[e] = s;
    }
    __syncthreads();

    // step 2: W rows for this (n2,m2)
    for (int e = threadIdx.x; e < N1 * M1 * M3; e += 256) {
        const int m3 = e % M3;
        const int m1 = (e / M3) % M1;
        const int n1 = e / (M3 * M1);
        const float* c0p = c0 + (n1 * M1 + m1) * 16;
        float acc[N3] = {};
#pragma unroll
        for (int r1 = 0; r1 < 16; ++r1) {
            const float c0v = c0p[r1];
#pragma unroll
            for (int n3 = 0; n3 < N3; ++n3)
                acc[n3] += c0v * S[(r1 * N3 + n3) * M3 + m3];
        }
        unsigned short ob[N3];
#pragma unroll
        for (int n3 = 0; n3 < N3; ++n3) ob[n3] = f2b(acc[n3]);
        unsigned short* dst = W + (size_t)((m1 * M2 + m2) * M3 + m3) * K
                                + (n1 * N2 + n2) * N3;
#pragma unroll
        for (int c = 0; c < N3 / 8; ++c)
            ((int4*)dst)[c] = ((const int4*)ob)[c];
    }
}

// prep_all: ONE launch for all pre-GEMM work.
//   blocks [0,256)    -> W1 (layer 1, (n2,m2) grid 16x16)
//   blocks [256,512)  -> W2 (layer 2, (n2,m2) grid 16x16)
//   blocks [512,2560) -> cvt x (f32, 16MB) -> xb (bf16), 8 elems/thread
__global__ __launch_bounds__(256)
void prep_all(const float* __restrict__ c10, const float* __restrict__ c11,
              const float* __restrict__ c12,
              const float* __restrict__ c20, const float* __restrict__ c21,
              const float* __restrict__ c22,
              const float* __restrict__ x, unsigned short* __restrict__ xb,
              unsigned short* __restrict__ W1, unsigned short* __restrict__ W2) {
    __shared__ float S[16 * 128];     // 8 KB: 16 r1 x (N3*M3 = 128 both layers)
    const int b = blockIdx.x;
    if (b < 256) {
        build_W_fused<8, 16, 8, 16, 16, 16>(b, c10, c11, c12, W1, S);
    } else if (b < 512) {
        build_W_fused<16, 16, 16, 8, 16, 8>(b - 256, c20, c21, c22, W2, S);
    } else {
        const int t = (b - 512) * 256 + threadIdx.x;
        const float4* p = (const float4*)(x + (size_t)t * 8);
        float4 f0 = p[0], f1 = p[1];
        int4 o;
        o.x = (uint32_t)f2b(f0.x) | ((uint32_t)f2b(f0.y) << 16);
        o.y = (uint32_t)f2b(f0.z) | ((uint32_t)f2b(f0.w) << 16);
        o.z = (uint32_t)f2b(f1.x) | ((uint32_t)f2b(f1.y) << 16);
        o.w = (uint32_t)f2b(f1.z) | ((uint32_t)f2b(f1.w) << 16);
        ((int4*)xb)[t] = o;
    }
}

// ---------------------------------------------------------------------------
// Fallback-path kernels (small workspace): verified R5-R7 chain.
// ---------------------------------------------------------------------------
template<int N3, int M3>
__device__ __forceinline__ void build_T_body(int e,
                                             const float* __restrict__ c1,
                                             const float* __restrict__ c2,
                                             float* __restrict__ T) {
    int m3 = e % M3;
    int t  = e / M3;
    int n3 = t % N3;
    int rm = t / N3;
    float s = 0.f;
#pragma unroll
    for (int r2 = 0; r2 < 16; ++r2)
        s += c1[rm * 16 + r2] * c2[(r2 * N3 + n3) * M3 + m3];
    T[e] = s;
}

__global__ __launch_bounds__(256)
void prep_stage1(const float* __restrict__ c11, const float* __restrict__ c12,
                 float* __restrict__ T1,
                 const float* __restrict__ c21, const float* __restrict__ c22,
                 float* __restrict__ T2,
                 const float* __restrict__ x, unsigned short* __restrict__ xb) {
    const int b = blockIdx.x;
    if (b < 2048) {
        build_T_body<8, 16>(b * 256 + threadIdx.x, c11, c12, T1);
    } else if (b < 4096) {
        build_T_body<16, 8>((b - 2048) * 256 + threadIdx.x, c21, c22, T2);
    } else {
        const int t = (b - 4096) * 256 + threadIdx.x;
        const float4* p = (const float4*)(x + (size_t)t * 8);
        float4 f0 = p[0], f1 = p[1];
        int4 o;
        o.x = (uint32_t)f2b(f0.x) | ((uint32_t)f2b(f0.y) << 16);
        o.y = (uint32_t)f2b(f0.z) | ((uint32_t)f2b(f0.w) << 16);
        o.z = (uint32_t)f2b(f1.x) | ((uint32_t)f2b(f1.y) << 16);
        o.w = (uint32_t)f2b(f1.z) | ((uint32_t)f2b(f1.w) << 16);
        ((int4*)xb)[t] = o;
    }
}

template<int N1, int N2, int N3, int M1, int M2, int M3>
__device__ __forceinline__ void build_W_body(int t,
                                             const float* __restrict__ c0,
                                             const float* __restrict__ T,
                                             unsigned short* __restrict__ W) {
    constexpr int K = N1 * N2 * N3;
    int m3 = t % M3;
    int m2 = (t / M3) % M2;
    int n2 = (t / (M3 * M2)) % N2;
    int m1 = (t / (M3 * M2 * N2)) % M1;
    int n1 =  t / (M3 * M2 * N2 * M1);

    float c0r[16];
    const float4* c0p = (const float4*)(c0 + (n1 * M1 + m1) * 16);
#pragma unroll
    for (int i = 0; i < 4; ++i) ((float4*)c0r)[i] = c0p[i];

    float acc[N3] = {};
#pragma unroll
    for (int r1 = 0; r1 < 16; ++r1) {
        const float* Tp = T + (size_t)(((r1 * 16 + n2) * 16 + m2) * N3) * M3 + m3;
#pragma unroll
        for (int n3 = 0; n3 < N3; ++n3)
            acc[n3] += c0r[r1] * Tp[n3 * M3];
    }

    unsigned short ob[N3];
#pragma unroll
    for (int n3 = 0; n3 < N3; ++n3) ob[n3] = f2b(acc[n3]);

    unsigned short* dst = W + (size_t)((m1 * M2 + m2) * M3 + m3) * K
                            + (n1 * N2 + n2) * N3;
#pragma unroll
    for (int c = 0; c < N3 / 8; ++c)
        ((int4*)dst)[c] = ((const int4*)ob)[c];
}

template<int N1, int N2, int N3, int M1, int M2, int M3>
__global__ __launch_bounds__(256)
void build_W(const float* __restrict__ c0, const float* __restrict__ T,
             unsigned short* __restrict__ W) {
    build_W_body<N1, N2, N3, M1, M2, M3>(blockIdx.x * 256 + threadIdx.x, c0, T, W);
}

// ---------------------------------------------------------------------------
// gemm_sb: SINGLE-buffered BK=64 2-barrier loop (R10-verified, 0 conflicts).
// 256 threads, all-wave compute, gload_lds staging with pre-swizzled source.
// 40KB LDS REQUEST caps occupancy at the gload_lds-safe 4 blocks/CU.
// NOTE (R10 measured): GEMM time is invariant (61-62us, 554 TF) across all
// __syncthreads-granularity structures at this shape -- do not restructure.
// C/D map (m74/m101): col=lane&31, row=(reg&3)+8*(reg>>2)+4*(lane>>5).
// ---------------------------------------------------------------------------
template<int BM, int BN, int KCH, int KSTR, int GX, int GY,
         bool DO_GELU, bool ATOMIC>
__global__ __launch_bounds__(256, 4)
void gemm_sb(const unsigned short* __restrict__ A,
             const unsigned short* __restrict__ Bt,
             const float* __restrict__ bias,
             void* __restrict__ Cv,
             int Ncols)
{
    constexpr int BK  = 64;
    constexpr int NT  = KCH / BK;
    constexpr int ASZ = BM * BK;           // elems
    constexpr int ACH = BM / 32;           // 4KB chunks (32 rows x 128B)
    constexpr int BCH = BN / 32;
    constexpr int FI  = BM / 64, FJ = BN / 64;

    extern __shared__ unsigned short sh[];   // [ASZ + BSZ] (40KB requested)

    const int tid   = threadIdx.x;
    const int lane  = tid & 63;
    const int wave  = tid >> 6;            // 0..3
    const int m32   = lane & 31;
    const int khalf = lane >> 5;
    const int waveM = (wave >> 1) * (BM / 2);
    const int waveN = (wave & 1) * (BN / 2);
    const int srow  = tid >> 3;            // staging row-within-chunk (0..31)
    const int sslot = tid & 7;             // staging 16B slot

    // XCD-chunked bijective block swizzle over (x,y,z); total % 8 == 0
    int lin = ((int)blockIdx.z * GY + (int)blockIdx.y) * GX + (int)blockIdx.x;
    const int total = GX * GY * (int)gridDim.z;
    lin = (lin & 7) * (total >> 3) + (lin >> 3);
    const int colBase = (lin % GX) * BN;
    const int rowBase = ((lin / GX) % GY) * BM;
    const int kOff    = (lin / (GX * GY)) * KCH;

#define SB_STAGE(K0_)                                                         \
    {                                                                         \
        _Pragma("unroll")                                                     \
        for (int c = 0; c < ACH; ++c) {                                       \
            const int r  = c * 32 + srow;                                     \
            const int jg = sslot ^ (r & 7) ^ ((r >> 3) & 7);                  \
            const unsigned short* src = A +                                   \
                (size_t)(rowBase + r) * KSTR + (K0_) + jg * 8;                \
            unsigned short* dst = sh + c * 2048 + wave * 512;                 \
            __builtin_amdgcn_global_load_lds(                                 \
                (const __attribute__((address_space(1))) void*)src,           \
                (__attribute__((address_space(3))) void*)dst, 16, 0, 0);      \
        }                                                                     \
        _Pragma("unroll")                                                     \
        for (int c = 0; c < BCH; ++c) {                                       \
            const int r  = c * 32 + srow;                                     \
            const int jg = sslot ^ (r & 7) ^ ((r >> 3) & 7);                  \
            const unsigned short* src = Bt +                                  \
                (size_t)(colBase + r) * KSTR + (K0_) + jg * 8;                \
            unsigned short* dst = sh + ASZ + c * 2048 + wave * 512;           \
            __builtin_amdgcn_global_load_lds(                                 \
                (const __attribute__((address_space(1))) void*)src,           \
                (__attribute__((address_space(3))) void*)dst, 16, 0, 0);      \
        }                                                                     \
    }

    f32x16 acc[FI][FJ] = {};

    for (int t = 0; t < NT; ++t) {
        SB_STAGE(kOff + t * BK)
        __syncthreads();                   // vm drain: tile t landed

        const unsigned short* Ab = sh;
        const unsigned short* Bb = sh + ASZ;
#pragma unroll
        for (int ks = 0; ks < 4; ++ks) {
            bf16x8 a_f[FI], b_f[FJ];
            const int g = ks * 2 + khalf;
#pragma unroll
            for (int i = 0; i < FI; ++i) {
                const int r = waveM + i * 32 + m32;
                const int key = (r & 7) ^ ((r >> 3) & 7);
                a_f[i] = *(const bf16x8*)&Ab[r * BK + ((g ^ key) << 3)];
            }
#pragma unroll
            for (int j = 0; j < FJ; ++j) {
                const int r = waveN + j * 32 + m32;
                const int key = (r & 7) ^ ((r >> 3) & 7);
                b_f[j] = *(const bf16x8*)&Bb[r * BK + ((g ^ key) << 3)];
            }
#pragma unroll
            for (int i = 0; i < FI; ++i)
#pragma unroll
                for (int j = 0; j < FJ; ++j)
                    acc[i][j] = __builtin_amdgcn_mfma_f32_32x32x16_bf16(
                        a_f[i], b_f[j], acc[i][j], 0, 0, 0);
        }
        if (t + 1 < NT) __syncthreads();   // reads done before next stage
    }
#undef SB_STAGE

    // epilogue: col=lane&31, row=(reg&3)+8*(reg>>2)+4*(lane>>5)
#pragma unroll
    for (int i = 0; i < FI; ++i) {
#pragma unroll
        for (int j = 0; j < FJ; ++j) {
            const int col = colBase + waveN + j * 32 + m32;
            const float bv = ATOMIC ? 0.f : bias[col];
#pragma unroll
            for (int reg = 0; reg < 16; ++reg) {
                const int row = rowBase + waveM + i * 32 +
                                (reg & 3) + 8 * (reg >> 2) + 4 * khalf;
                const size_t off = (size_t)row * Ncols + col;
                if (ATOMIC) {
                    unsafeAtomicAdd((float*)Cv + off, acc[i][j][reg]);
                } else {
                    float z = acc[i][j][reg] + bv;
                    if (DO_GELU)
                        z = 0.5f * z * (1.f + erff(z * 0.70710678118654752f));
                    if (ATOMIC) ((float*)Cv)[off] = z;  // unreachable
                    else if (DO_GELU) ((unsigned short*)Cv)[off] = f2b(z);
                    else ((float*)Cv)[off] = z;
                }
            }
        }
    }
}

// ---------------------------------------------------------------------------
// gemm_pc: R0's producer-consumer GEMM (fallback path; 62us/GEMM proven).
// ---------------------------------------------------------------------------
#define PC_COMPUTE(BUF)                                                       \
    {                                                                         \
        _Pragma("unroll")                                                     \
        for (int ks = 0; ks < 4; ++ks) {                                      \
            bf16x8 a_f[FI], b_f[FJ];                                          \
            _Pragma("unroll")                                                 \
            for (int i = 0; i < FI; ++i) {                                    \
                const int key = (m32 & 7) ^                                   \
                    (((waveM >> 3) + 4 * i + (m32 >> 3)) & 7);                \
                const int slot = ((ks * 2 + khalf) ^ key) * 8;                \
                a_f[i] = *(const bf16x8*)&As[(BUF) * ASZ +                    \
                          (waveM + i * 32 + m32) * BK + slot];                \
            }                                                                 \
            _Pragma("unroll")                                                 \
            for (int j = 0; j < FJ; ++j) {                                    \
                const int key = (m32 & 7) ^                                   \
                    (((waveN >> 3) + 4 * j + (m32 >> 3)) & 7);                \
                const int slot = ((ks * 2 + khalf) ^ key) * 8;                \
                b_f[j] = *(const bf16x8*)&Bs[(BUF) * BSZ +                    \
                          (waveN + j * 32 + m32) * BK + slot];                \
            }                                                                 \
            _Pragma("unroll")                                                 \
            for (int i = 0; i < FI; ++i)                                      \
                _Pragma("unroll")                                             \
                for (int j = 0; j < FJ; ++j)                                  \
                    acc[i][j] = __builtin_amdgcn_mfma_f32_32x32x16_bf16(      \
                        a_f[i], b_f[j], acc[i][j], 0, 0, 0);                  \
        }                                                                     \
    }

template<int BM, int BN, int KTOT, bool DO_GELU, bool A_F32, bool C_F32>
__global__ __launch_bounds__(512, 4)
void gemm_pc(const void* __restrict__ Av,
             const unsigned short* __restrict__ Bt,
             const float* __restrict__ bias,
             void* __restrict__ Cv,
             int Ncols) {
    constexpr int BK  = 64;
    constexpr int CA  = BM / 8;
    constexpr int CB  = BN / 8;
    constexpr int PA  = CA / 4;
    constexpr int PB  = CB / 4;
    constexpr int FI  = BM / 64;
    constexpr int FJ  = BN / 64;
    constexpr int ASZ = BM * BK;
    constexpr int BSZ = BN * BK;
    __shared__ unsigned short As[2 * ASZ];
    __shared__ unsigned short Bs[2 * BSZ];

    const int tid  = threadIdx.x;
    const int lane = tid & 63;
    const int wave = tid >> 6;
    const int rowBase = blockIdx.y * BM;
    const int colBase = blockIdx.x * BN;

    const int lr    = lane >> 3;
    const int jj    = lane & 7;
    const int m32   = lane & 31;
    const int khalf = lane >> 5;

    if (wave >= 4) {
        const int pw = wave - 4;
#pragma unroll
        for (int it = 0; it < PA; ++it) {
            const int c  = pw * PA + it;
            const int jg = jj ^ lr ^ (c & 7);
            const size_t aoff = (size_t)(rowBase + c * 8 + lr) * KTOT + jg * 8;
            int4 v;
            if (A_F32) {
                const float* ga = (const float*)Av + aoff;
                float4 f0 = *(const float4*)ga;
                float4 f1 = *(const float4*)(ga + 4);
                v.x = (uint32_t)f2b(f0.x) | ((uint32_t)f2b(f0.y) << 16);
                v.y = (uint32_t)f2b(f0.z) | ((uint32_t)f2b(f0.w) << 16);
                v.z = (uint32_t)f2b(f1.x) | ((uint32_t)f2b(f1.y) << 16);
                v.w = (uint32_t)f2b(f1.z) | ((uint32_t)f2b(f1.w) << 16);
            } else {
                v = *(const int4*)((const unsigned short*)Av + aoff);
            }
            *(int4*)&As[c * 512 + lane * 8] = v;
        }
#pragma unroll
        for (int it = 0; it < PB; ++it) {
            const int c  = pw * PB + it;
            const int jg = jj ^ lr ^ (c & 7);
            *(int4*)&Bs[c * 512 + lane * 8] =
                *(const int4*)(Bt + (size_t)(colBase + c * 8 + lr) * KTOT + jg * 8);
        }
        __syncthreads();

        int buf = 1;
        for (int k0 = BK; k0 < KTOT; k0 += BK) {
            int4 aR[PA], bR[PB];
#pragma unroll
            for (int it = 0; it < PA; ++it) {
                const int c  = pw * PA + it;
                const int jg = jj ^ lr ^ (c & 7);
                const size_t aoff = (size_t)(rowBase + c * 8 + lr) * KTOT + k0 + jg * 8;
                if (A_F32) {
                    const float* ga = (const float*)Av + aoff;
                    float4 f0 = *(const float4*)ga;
                    float4 f1 = *(const float4*)(ga + 4);
                    int4 v;
                    v.x = (uint32_t)f2b(f0.x) | ((uint32_t)f2b(f0.y) << 16);
                    v.y = (uint32_t)f2b(f0.z) | ((uint32_t)f2b(f0.w) << 16);
                    v.z = (uint32_t)f2b(f1.x) | ((uint32_t)f2b(f1.y) << 16);
                    v.w = (uint32_t)f2b(f1.z) | ((uint32_t)f2b(f1.w) << 16);
                    aR[it] = v;
                } else {
                    aR[it] = *(const int4*)((const unsigned short*)Av + aoff);
                }
            }
#pragma unroll
            for (int it = 0; it < PB; ++it) {
                const int c  = pw * PB + it;
                const int jg = jj ^ lr ^ (c & 7);
                bR[it] = *(const int4*)(Bt + (size_t)(colBase + c * 8 + lr) * KTOT + k0 + jg * 8);
            }
#pragma unroll
            for (int it = 0; it < PA; ++it) {
                const int c = pw * PA + it;
                *(int4*)&As[buf * ASZ + c * 512 + lane * 8] = aR[it];
            }
#pragma unroll
            for (int it = 0; it < PB; ++it) {
                const int c = pw * PB + it;
                *(int4*)&Bs[buf * BSZ + c * 512 + lane * 8] = bR[it];
            }
            __syncthreads();
            buf ^= 1;
        }
    } else {
        const int waveM = (wave >> 1) * (BM / 2);
        const int waveN = (wave & 1) * (BN / 2);
        f32x16 acc[FI][FJ] = {};

        __syncthreads();

        int cur = 0;
        for (int k0 = BK; k0 < KTOT; k0 += BK) {
            PC_COMPUTE(cur)
            __syncthreads();
            cur ^= 1;
        }
        PC_COMPUTE(cur)

#pragma unroll
        for (int i = 0; i < FI; ++i) {
#pragma unroll
            for (int j = 0; j < FJ; ++j) {
                const int col = colBase + waveN + j * 32 + m32;
                const float bv = bias[col];
#pragma unroll
                for (int reg = 0; reg < 16; ++reg) {
                    const int row = rowBase + waveM + i * 32 +
                                    (reg & 3) + 8 * (reg >> 2) + 4 * khalf;
                    float z = acc[i][j][reg] + bv;
                    if (DO_GELU)
                        z = 0.5f * z * (1.f + erff(z * 0.70710678118654752f));
                    const size_t off = (size_t)row * Ncols + col;
                    if (C_F32) ((float*)Cv)[off] = z;
                    else       ((unsigned short*)Cv)[off] = f2b(z);
                }
            }
        }
    }
}

// ---------------------------------------------------------------------------
extern "C" void kernel_launch(void* const* d_in, const int* in_sizes, int n_in,
                              void* d_out, int out_size, void* d_ws, size_t ws_size,
                              hipStream_t stream) {
    const float* x      = (const float*)d_in[0];   // [4096,1024] fp32
    const float* fc1_c0 = (const float*)d_in[1];
    const float* fc1_c1 = (const float*)d_in[2];
    const float* fc1_c2 = (const float*)d_in[3];
    const float* fc1_b  = (const float*)d_in[4];
    const float* fc2_c0 = (const float*)d_in[5];
    const float* fc2_c1 = (const float*)d_in[6];
    const float* fc2_c2 = (const float*)d_in[7];
    const float* fc2_b  = (const float*)d_in[8];

    char* ws = (char*)d_ws;
    const bool big = ws_size >= (48ull << 20);

    // 40KB LDS request -> occupancy = floor(160/40) = 4 blocks/CU exactly
    // (the documented-safe gload_lds maximum; verified R9/R10).
    constexpr int DLDS = 40 << 10;

    if (big) {
        // d_out scratch: xb bf16 [0,8M) -- dead before GEMM2 writes d_out.
        // ws: W1 [0,8M), W2 [8,16M), h bf16 [16,48M)
        unsigned short* xb = (unsigned short*)d_out;
        unsigned short* W1 = (unsigned short*)ws;
        unsigned short* W2 = (unsigned short*)(ws + (8u << 20));
        unsigned short* h  = (unsigned short*)(ws + (16u << 20));

        // K0: everything pre-GEMM in ONE launch:
        //     W1 (256 blocks) + W2 (256) + cvt x->xb (2048)
        prep_all<<<2560, 256, 0, stream>>>(fc1_c0, fc1_c1, fc1_c2,
                                           fc2_c0, fc2_c1, fc2_c2,
                                           x, xb, W1, W2);
        // K1: GEMM1 [4096,1024]x[1024,4096]^T + bias + GELU -> h (bf16)
        gemm_sb<128, 128, 1024, 1024, 32, 32, true, false>
            <<<dim3(32, 32, 1), 256, DLDS, stream>>>(xb, W1, fc1_b, h, 4096);
        // K2: GEMM2 [4096,4096]x[4096,1024]^T + bias -> d_out (f32, direct)
        gemm_sb<128, 64, 4096, 4096, 16, 32, false, false>
            <<<dim3(16, 32, 1), 256, DLDS, stream>>>(h, W2, fc2_b, d_out, 1024);
    } else {
        // Fallback (R7-verified chain): d_out scratch T1/T2/xb, ws W + h.
        float* T1 = (float*)d_out;
        float* T2 = (float*)d_out + 524288;
        unsigned short* xb = (unsigned short*)((char*)d_out + (4u << 20));
        unsigned short* W = (unsigned short*)ws;
        unsigned short* h = (unsigned short*)(ws + (8u << 20));

        prep_stage1<<<6144, 256, 0, stream>>>(fc1_c1, fc1_c2, T1,
                                              fc2_c1, fc2_c2, T2, x, xb);
        build_W<8, 16, 8, 16, 16, 16><<<2048, 256, 0, stream>>>(fc1_c0, T1, W);
        gemm_pc<128, 128, 1024, true, false, false>
            <<<dim3(32, 32), 512, 0, stream>>>(xb, W, fc1_b, h, 4096);
        build_W<16, 16, 16, 8, 16, 8><<<1024, 256, 0, stream>>>(fc2_c0, T2, W);
        gemm_pc<128, 64, 4096, false, false, true>
            <<<dim3(16, 32), 512, 0, stream>>>(h, W, fc2_b, d_out, 1024);
    }
}

// Round 12
// 211.042 us; speedup vs baseline: 1.1790x; 1.0030x over previous
//
#include <hip/hip_runtime.h>
#include <stdint.h>

// ---------- bf16 helpers (storage = unsigned short) ----------
__device__ __forceinline__ float b2f(unsigned short u) {
    union { uint32_t i; float f; } v; v.i = ((uint32_t)u) << 16; return v.f;
}
__device__ __forceinline__ unsigned short f2b(float f) {
    union { float f; uint32_t i; } v; v.f = f;
    uint32_t r = v.i + 0x7fffu + ((v.i >> 16) & 1u);   // RNE
    return (unsigned short)(r >> 16);
}

typedef __bf16 bf16x8 __attribute__((ext_vector_type(8)));
typedef float  f32x16 __attribute__((ext_vector_type(16)));

// ---------------------------------------------------------------------------
// build_W_fused + prep_all: ONE launch for all pre-GEMM work (R11-verified).
// ---------------------------------------------------------------------------
template<int N1, int N2, int N3, int M1, int M2, int M3>
__device__ __forceinline__ void build_W_fused(int blk,
                                              const float* __restrict__ c0,
                                              const float* __restrict__ c1,
                                              const float* __restrict__ c2,
                                              unsigned short* __restrict__ W,
                                              float* __restrict__ S) {
    constexpr int K = N1 * N2 * N3;
    const int n2 = blk / M2;
    const int m2 = blk % M2;

    for (int e = threadIdx.x; e < 16 * N3 * M3; e += 256) {
        const int m3 = e % M3;
        const int n3 = (e / M3) % N3;
        const int r1 = e / (M3 * N3);
        const float* c1p = c1 + ((r1 * N2 + n2) * M2 + m2) * 16;
        float s = 0.f;
#pragma unroll
        for (int r2 = 0; r2 < 16; ++r2)
            s += c1p[r2] * c2[(r2 * N3 + n3) * M3 + m3];
        S[e] = s;
    }
    __syncthreads();

    for (int e = threadIdx.x; e < N1 * M1 * M3; e += 256) {
        const int m3 = e % M3;
        const int m1 = (e / M3) % M1;
        const int n1 = e / (M3 * M1);
        const float* c0p = c0 + (n1 * M1 + m1) * 16;
        float acc[N3] = {};
#pragma unroll
        for (int r1 = 0; r1 < 16; ++r1) {
            const float c0v = c0p[r1];
#pragma unroll
            for (int n3 = 0; n3 < N3; ++n3)
                acc[n3] += c0v * S[(r1 * N3 + n3) * M3 + m3];
        }
        unsigned short ob[N3];
#pragma unroll
        for (int n3 = 0; n3 < N3; ++n3) ob[n3] = f2b(acc[n3]);
        unsigned short* dst = W + (size_t)((m1 * M2 + m2) * M3 + m3) * K
                                + (n1 * N2 + n2) * N3;
#pragma unroll
        for (int c = 0; c < N3 / 8; ++c)
            ((int4*)dst)[c] = ((const int4*)ob)[c];
    }
}

__global__ __launch_bounds__(256)
void prep_all(const float* __restrict__ c10, const float* __restrict__ c11,
              const float* __restrict__ c12,
              const float* __restrict__ c20, const float* __restrict__ c21,
              const float* __restrict__ c22,
              const float* __restrict__ x, unsigned short* __restrict__ xb,
              unsigned short* __restrict__ W1, unsigned short* __restrict__ W2) {
    __shared__ float S[16 * 128];
    const int b = blockIdx.x;
    if (b < 256) {
        build_W_fused<8, 16, 8, 16, 16, 16>(b, c10, c11, c12, W1, S);
    } else if (b < 512) {
        build_W_fused<16, 16, 16, 8, 16, 8>(b - 256, c20, c21, c22, W2, S);
    } else {
        const int t = (b - 512) * 256 + threadIdx.x;
        const float4* p = (const float4*)(x + (size_t)t * 8);
        float4 f0 = p[0], f1 = p[1];
        int4 o;
        o.x = (uint32_t)f2b(f0.x) | ((uint32_t)f2b(f0.y) << 16);
        o.y = (uint32_t)f2b(f0.z) | ((uint32_t)f2b(f0.w) << 16);
        o.z = (uint32_t)f2b(f1.x) | ((uint32_t)f2b(f1.y) << 16);
        o.w = (uint32_t)f2b(f1.z) | ((uint32_t)f2b(f1.w) << 16);
        ((int4*)xb)[t] = o;
    }
}

// ---------------------------------------------------------------------------
// Fallback-path kernels (small workspace): verified R5-R7 chain.
// ---------------------------------------------------------------------------
template<int N3, int M3>
__device__ __forceinline__ void build_T_body(int e,
                                             const float* __restrict__ c1,
                                             const float* __restrict__ c2,
                                             float* __restrict__ T) {
    int m3 = e % M3;
    int t  = e / M3;
    int n3 = t % N3;
    int rm = t / N3;
    float s = 0.f;
#pragma unroll
    for (int r2 = 0; r2 < 16; ++r2)
        s += c1[rm * 16 + r2] * c2[(r2 * N3 + n3) * M3 + m3];
    T[e] = s;
}

__global__ __launch_bounds__(256)
void prep_stage1(const float* __restrict__ c11, const float* __restrict__ c12,
                 float* __restrict__ T1,
                 const float* __restrict__ c21, const float* __restrict__ c22,
                 float* __restrict__ T2,
                 const float* __restrict__ x, unsigned short* __restrict__ xb) {
    const int b = blockIdx.x;
    if (b < 2048) {
        build_T_body<8, 16>(b * 256 + threadIdx.x, c11, c12, T1);
    } else if (b < 4096) {
        build_T_body<16, 8>((b - 2048) * 256 + threadIdx.x, c21, c22, T2);
    } else {
        const int t = (b - 4096) * 256 + threadIdx.x;
        const float4* p = (const float4*)(x + (size_t)t * 8);
        float4 f0 = p[0], f1 = p[1];
        int4 o;
        o.x = (uint32_t)f2b(f0.x) | ((uint32_t)f2b(f0.y) << 16);
        o.y = (uint32_t)f2b(f0.z) | ((uint32_t)f2b(f0.w) << 16);
        o.z = (uint32_t)f2b(f1.x) | ((uint32_t)f2b(f1.y) << 16);
        o.w = (uint32_t)f2b(f1.z) | ((uint32_t)f2b(f1.w) << 16);
        ((int4*)xb)[t] = o;
    }
}

template<int N1, int N2, int N3, int M1, int M2, int M3>
__device__ __forceinline__ void build_W_body(int t,
                                             const float* __restrict__ c0,
                                             const float* __restrict__ T,
                                             unsigned short* __restrict__ W) {
    constexpr int K = N1 * N2 * N3;
    int m3 = t % M3;
    int m2 = (t / M3) % M2;
    int n2 = (t / (M3 * M2)) % N2;
    int m1 = (t / (M3 * M2 * N2)) % M1;
    int n1 =  t / (M3 * M2 * N2 * M1);

    float c0r[16];
    const float4* c0p = (const float4*)(c0 + (n1 * M1 + m1) * 16);
#pragma unroll
    for (int i = 0; i < 4; ++i) ((float4*)c0r)[i] = c0p[i];

    float acc[N3] = {};
#pragma unroll
    for (int r1 = 0; r1 < 16; ++r1) {
        const float* Tp = T + (size_t)(((r1 * 16 + n2) * 16 + m2) * N3) * M3 + m3;
#pragma unroll
        for (int n3 = 0; n3 < N3; ++n3)
            acc[n3] += c0r[r1] * Tp[n3 * M3];
    }

    unsigned short ob[N3];
#pragma unroll
    for (int n3 = 0; n3 < N3; ++n3) ob[n3] = f2b(acc[n3]);

    unsigned short* dst = W + (size_t)((m1 * M2 + m2) * M3 + m3) * K
                            + (n1 * N2 + n2) * N3;
#pragma unroll
    for (int c = 0; c < N3 / 8; ++c)
        ((int4*)dst)[c] = ((const int4*)ob)[c];
}

template<int N1, int N2, int N3, int M1, int M2, int M3>
__global__ __launch_bounds__(256)
void build_W(const float* __restrict__ c0, const float* __restrict__ T,
             unsigned short* __restrict__ W) {
    build_W_body<N1, N2, N3, M1, M2, M3>(blockIdx.x * 256 + threadIdx.x, c0, T, W);
}

// ---------------------------------------------------------------------------
// gemm_8p: phase-pipelined GEMM (T3+T4+T5) -- the m201 schedule in plain HIP.
//
// 256x128 tile, BK=64, 512 threads = 8 waves (4M x 2N -> 64x64 wave tile:
// MFMA wall 1024cy/tile vs LDS-read 512cy -> MFMA-bound 2:1).  3-slot LDS
// ring (3 x 48KB = 144KB, 1 block/CU).
//
// Ring ledger: during tile t, stage tile t+2 into slot (t+2)%3 = slot
// (t-1)%3, whose reads finished at the end-of-(t-1) barrier.  End of tile
// t: s_waitcnt vmcnt(6) -- exactly tile t+2's 6 loads/wave may remain in
// flight => tile t+1 fully landed.  Loads NEVER drain to 0 mid-loop (T4).
// Prologue: tiles 0,1 -> slots 0,1; vmcnt(6) => tile 0 landed.
// Tails: t+2>=NT stages nothing; end-of-(NT-2) uses vmcnt(0).
//
// Per phase (4 phases/tile, ph = k16-step): {4x ds_read_b128 frags ||
// issue 2 gload_lds of tile t+2} -> s_barrier -> setprio(1) -> 4x
// mfma_32x32x16 -> setprio(0) -> s_barrier.  No hand lgkm waits: the
// compiler auto-inserts lgkmcnt before MFMA's register use (rule-18 hazard
// avoided by not using asm there).  The ONLY asm is the per-tile vmcnt
// (memory-clobbered so ds_reads can't hoist above it); R6's spill came
// from per-phase clobbers + register staging -- both absent here.
//
// Staging: 1KB chunks, chunk c = wave*6 + u (wave-uniform dst = slot +
// c*1024; HW adds lane*16).  c<32 -> A row c*8+(lane>>3); else B row
// (c-32)*8+(lane>>3).  Pre-swizzled source chunk jg = (lane&7) ^ key(r),
// key(r) = (r&7)^((r>>3)&7) -- the proven-0-conflict BK=64 swizzle; read
// slot = (ph*2+khalf) ^ key(r), identical family to gemm_sb.
// C/D map (m74/m101): col=lane&31, row=(reg&3)+8*(reg>>2)+4*(lane>>5).
// ---------------------------------------------------------------------------
template<int BM, int BN, int KTOT, int GX, bool DO_GELU>
__global__ __launch_bounds__(512, 2)
void gemm_8p(const unsigned short* __restrict__ A,
             const unsigned short* __restrict__ Bt,
             const float* __restrict__ bias,
             unsigned short* __restrict__ C,
             int Ncols)
{
    constexpr int BK   = 64;
    constexpr int NT   = KTOT / BK;
    constexpr int AE   = BM * BK;                  // 16384 elems (32KB)
    constexpr int SLOT = (BM + BN) * BK;           // 24576 elems (48KB)
    constexpr int ACH  = (AE * 2) / 1024;          // 32 A-chunks of 1KB
    constexpr int CPW  = ((SLOT * 2) / 1024) / 8;  // 6 chunks per wave

    extern __shared__ unsigned short sh[];         // 3 * SLOT elems

    const int tid   = threadIdx.x;
    const int lane  = tid & 63;
    const int wave  = tid >> 6;           // 0..7
    const int m32   = lane & 31;
    const int kh    = lane >> 5;
    const int waveM = (wave >> 1) * 64;   // 4 M-waves
    const int waveN = (wave & 1) * 64;    // 2 N-waves
    const int srow8 = lane >> 3;          // row within 8-row chunk
    const int sslot = lane & 7;           // 16B slot within 128B row

    // XCD-chunked bijective block swizzle (total = 512, %8==0)
    int lin = (int)blockIdx.y * GX + (int)blockIdx.x;
    const int total = GX * (int)gridDim.y;
    lin = (lin & 7) * (total >> 3) + (lin >> 3);
    const int colBase = (lin % GX) * BN;
    const int rowBase = (lin / GX) * BM;

#define P8_STAGE(TS_, KK_, U_)                                                \
    {                                                                         \
        const int c_   = wave * CPW + (U_);                                   \
        const bool b_  = c_ >= ACH;                                           \
        const int r_   = (b_ ? c_ - ACH : c_) * 8 + srow8;                    \
        const int jg_  = sslot ^ (r_ & 7) ^ ((r_ >> 3) & 7);                  \
        const unsigned short* s_ = (b_ ?                                      \
            Bt + (size_t)(colBase + r_) * KTOT :                              \
            A  + (size_t)(rowBase + r_) * KTOT) + (KK_) + jg_ * 8;            \
        unsigned short* d_ = sh + (TS_) + c_ * 512;                           \
        __builtin_amdgcn_global_load_lds(                                     \
            (const __attribute__((address_space(1))) void*)s_,                \
            (__attribute__((address_space(3))) void*)d_, 16, 0, 0);           \
    }

    f32x16 acc[2][2] = {};

    // ---- prologue: tiles 0,1 -> slots 0,1; tile 0 landed, tile 1 in flight
#pragma unroll
    for (int u = 0; u < CPW; ++u) P8_STAGE(0, 0, u)
#pragma unroll
    for (int u = 0; u < CPW; ++u) P8_STAGE(SLOT, BK, u)
    asm volatile("s_waitcnt vmcnt(%0)" :: "n"(CPW) : "memory");
    __builtin_amdgcn_s_barrier();

    for (int t = 0; t < NT; ++t) {
        const unsigned short* Ab = sh + (t % 3) * SLOT;
        const unsigned short* Bb = Ab + AE;
        const int ts = ((t + 2) % 3) * SLOT;
        const int kk = (t + 2) * BK;
        const bool doStage = (t + 2 < NT);

#pragma unroll
        for (int ph = 0; ph < 4; ++ph) {
            bf16x8 af[2], bfr[2];
            const int g = ph * 2 + kh;
#pragma unroll
            for (int i = 0; i < 2; ++i) {
                const int r = waveM + i * 32 + m32;
                const int key = (r & 7) ^ ((r >> 3) & 7);
                af[i] = *(const bf16x8*)&Ab[r * BK + ((g ^ key) << 3)];
            }
#pragma unroll
            for (int j = 0; j < 2; ++j) {
                const int r = waveN + j * 32 + m32;
                const int key = (r & 7) ^ ((r >> 3) & 7);
                bfr[j] = *(const bf16x8*)&Bb[r * BK + ((g ^ key) << 3)];
            }
            if (doStage && ph < 3) {
                P8_STAGE(ts, kk, ph * 2)
                P8_STAGE(ts, kk, ph * 2 + 1)
            }
            __builtin_amdgcn_s_barrier();
            __builtin_amdgcn_s_setprio(1);
#pragma unroll
            for (int i = 0; i < 2; ++i)
#pragma unroll
                for (int j = 0; j < 2; ++j)
                    acc[i][j] = __builtin_amdgcn_mfma_f32_32x32x16_bf16(
                        af[i], bfr[j], acc[i][j], 0, 0, 0);
            __builtin_amdgcn_s_setprio(0);
            __builtin_amdgcn_s_barrier();
        }

        // end of tile: ensure t+1 landed; never drain to 0 mid-loop
        if (t + 2 < NT) {
            asm volatile("s_waitcnt vmcnt(%0)" :: "n"(CPW) : "memory");
        } else if (t + 1 < NT) {
            asm volatile("s_waitcnt vmcnt(0)" ::: "memory");
        }
        if (t + 1 < NT) __builtin_amdgcn_s_barrier();
    }
#undef P8_STAGE

    // epilogue: col=lane&31, row=(reg&3)+8*(reg>>2)+4*(lane>>5)
#pragma unroll
    for (int i = 0; i < 2; ++i) {
#pragma unroll
        for (int j = 0; j < 2; ++j) {
            const int col = colBase + waveN + j * 32 + m32;
            const float bv = bias[col];
#pragma unroll
            for (int reg = 0; reg < 16; ++reg) {
                const int row = rowBase + waveM + i * 32 +
                                (reg & 3) + 8 * (reg >> 2) + 4 * kh;
                float z = acc[i][j][reg] + bv;
                if (DO_GELU)
                    z = 0.5f * z * (1.f + erff(z * 0.70710678118654752f));
                C[(size_t)row * Ncols + col] = f2b(z);
            }
        }
    }
}

// ---------------------------------------------------------------------------
// gemm_sb: SINGLE-buffered BK=64 2-barrier loop (R10/R11-verified).
// 40KB LDS request caps occupancy at the gload_lds-safe 4 blocks/CU.
// ---------------------------------------------------------------------------
template<int BM, int BN, int KCH, int KSTR, int GX, int GY,
         bool DO_GELU, bool ATOMIC>
__global__ __launch_bounds__(256, 4)
void gemm_sb(const unsigned short* __restrict__ A,
             const unsigned short* __restrict__ Bt,
             const float* __restrict__ bias,
             void* __restrict__ Cv,
             int Ncols)
{
    constexpr int BK  = 64;
    constexpr int NT  = KCH / BK;
    constexpr int ASZ = BM * BK;
    constexpr int ACH = BM / 32;
    constexpr int BCH = BN / 32;
    constexpr int FI  = BM / 64, FJ = BN / 64;

    extern __shared__ unsigned short sh[];

    const int tid   = threadIdx.x;
    const int lane  = tid & 63;
    const int wave  = tid >> 6;
    const int m32   = lane & 31;
    const int khalf = lane >> 5;
    const int waveM = (wave >> 1) * (BM / 2);
    const int waveN = (wave & 1) * (BN / 2);
    const int srow  = tid >> 3;
    const int sslot = tid & 7;

    int lin = ((int)blockIdx.z * GY + (int)blockIdx.y) * GX + (int)blockIdx.x;
    const int total = GX * GY * (int)gridDim.z;
    lin = (lin & 7) * (total >> 3) + (lin >> 3);
    const int colBase = (lin % GX) * BN;
    const int rowBase = ((lin / GX) % GY) * BM;
    const int kOff    = (lin / (GX * GY)) * KCH;

#define SB_STAGE(K0_)                                                         \
    {                                                                         \
        _Pragma("unroll")                                                     \
        for (int c = 0; c < ACH; ++c) {                                       \
            const int r  = c * 32 + srow;                                     \
            const int jg = sslot ^ (r & 7) ^ ((r >> 3) & 7);                  \
            const unsigned short* src = A +                                   \
                (size_t)(rowBase + r) * KSTR + (K0_) + jg * 8;                \
            unsigned short* dst = sh + c * 2048 + wave * 512;                 \
            __builtin_amdgcn_global_load_lds(                                 \
                (const __attribute__((address_space(1))) void*)src,           \
                (__attribute__((address_space(3))) void*)dst, 16, 0, 0);      \
        }                                                                     \
        _Pragma("unroll")                                                     \
        for (int c = 0; c < BCH; ++c) {                                       \
            const int r  = c * 32 + srow;                                     \
            const int jg = sslot ^ (r & 7) ^ ((r >> 3) & 7);                  \
            const unsigned short* src = Bt +                                  \
                (size_t)(colBase + r) * KSTR + (K0_) + jg * 8;                \
            unsigned short* dst = sh + ASZ + c * 2048 + wave * 512;           \
            __builtin_amdgcn_global_load_lds(                                 \
                (const __attribute__((address_space(1))) void*)src,           \
                (__attribute__((address_space(3))) void*)dst, 16, 0, 0);      \
        }                                                                     \
    }

    f32x16 acc[FI][FJ] = {};

    for (int t = 0; t < NT; ++t) {
        SB_STAGE(kOff + t * BK)
        __syncthreads();

        const unsigned short* Ab = sh;
        const unsigned short* Bb = sh + ASZ;
#pragma unroll
        for (int ks = 0; ks < 4; ++ks) {
            bf16x8 a_f[FI], b_f[FJ];
            const int g = ks * 2 + khalf;
#pragma unroll
            for (int i = 0; i < FI; ++i) {
                const int r = waveM + i * 32 + m32;
                const int key = (r & 7) ^ ((r >> 3) & 7);
                a_f[i] = *(const bf16x8*)&Ab[r * BK + ((g ^ key) << 3)];
            }
#pragma unroll
            for (int j = 0; j < FJ; ++j) {
                const int r = waveN + j * 32 + m32;
                const int key = (r & 7) ^ ((r >> 3) & 7);
                b_f[j] = *(const bf16x8*)&Bb[r * BK + ((g ^ key) << 3)];
            }
#pragma unroll
            for (int i = 0; i < FI; ++i)
#pragma unroll
                for (int j = 0; j < FJ; ++j)
                    acc[i][j] = __builtin_amdgcn_mfma_f32_32x32x16_bf16(
                        a_f[i], b_f[j], acc[i][j], 0, 0, 0);
        }
        if (t + 1 < NT) __syncthreads();
    }
#undef SB_STAGE

#pragma unroll
    for (int i = 0; i < FI; ++i) {
#pragma unroll
        for (int j = 0; j < FJ; ++j) {
            const int col = colBase + waveN + j * 32 + m32;
            const float bv = ATOMIC ? 0.f : bias[col];
#pragma unroll
            for (int reg = 0; reg < 16; ++reg) {
                const int row = rowBase + waveM + i * 32 +
                                (reg & 3) + 8 * (reg >> 2) + 4 * khalf;
                const size_t off = (size_t)row * Ncols + col;
                if (ATOMIC) {
                    unsafeAtomicAdd((float*)Cv + off, acc[i][j][reg]);
                } else {
                    float z = acc[i][j][reg] + bv;
                    if (DO_GELU) {
                        z = 0.5f * z * (1.f + erff(z * 0.70710678118654752f));
                        ((unsigned short*)Cv)[off] = f2b(z);
                    } else {
                        ((float*)Cv)[off] = z;
                    }
                }
            }
        }
    }
}

// ---------------------------------------------------------------------------
// gemm_pc: R0's producer-consumer GEMM (fallback path only).
// ---------------------------------------------------------------------------
#define PC_COMPUTE(BUF)                                                       \
    {                                                                         \
        _Pragma("unroll")                                                     \
        for (int ks = 0; ks < 4; ++ks) {                                      \
            bf16x8 a_f[FI], b_f[FJ];                                          \
            _Pragma("unroll")                                                 \
            for (int i = 0; i < FI; ++i) {                                    \
                const int key = (m32 & 7) ^                                   \
                    (((waveM >> 3) + 4 * i + (m32 >> 3)) & 7);                \
                const int slot = ((ks * 2 + khalf) ^ key) * 8;                \
                a_f[i] = *(const bf16x8*)&As[(BUF) * ASZ +                    \
                          (waveM + i * 32 + m32) * BK + slot];                \
            }                                                                 \
            _Pragma("unroll")                                                 \
            for (int j = 0; j < FJ; ++j) {                                    \
                const int key = (m32 & 7) ^                                   \
                    (((waveN >> 3) + 4 * j + (m32 >> 3)) & 7);                \
                const int slot = ((ks * 2 + khalf) ^ key) * 8;                \
                b_f[j] = *(const bf16x8*)&Bs[(BUF) * BSZ +                    \
                          (waveN + j * 32 + m32) * BK + slot];                \
            }                                                                 \
            _Pragma("unroll")                                                 \
            for (int i = 0; i < FI; ++i)                                      \
                _Pragma("unroll")                                             \
                for (int j = 0; j < FJ; ++j)                                  \
                    acc[i][j] = __builtin_amdgcn_mfma_f32_32x32x16_bf16(      \
                        a_f[i], b_f[j], acc[i][j], 0, 0, 0);                  \
        }                                                                     \
    }

template<int BM, int BN, int KTOT, bool DO_GELU, bool A_F32, bool C_F32>
__global__ __launch_bounds__(512, 4)
void gemm_pc(const void* __restrict__ Av,
             const unsigned short* __restrict__ Bt,
             const float* __restrict__ bias,
             void* __restrict__ Cv,
             int Ncols) {
    constexpr int BK  = 64;
    constexpr int CA  = BM / 8;
    constexpr int CB  = BN / 8;
    constexpr int PA  = CA / 4;
    constexpr int PB  = CB / 4;
    constexpr int FI  = BM / 64;
    constexpr int FJ  = BN / 64;
    constexpr int ASZ = BM * BK;
    constexpr int BSZ = BN * BK;
    __shared__ unsigned short As[2 * ASZ];
    __shared__ unsigned short Bs[2 * BSZ];

    const int tid  = threadIdx.x;
    const int lane = tid & 63;
    const int wave = tid >> 6;
    const int rowBase = blockIdx.y * BM;
    const int colBase = blockIdx.x * BN;

    const int lr    = lane >> 3;
    const int jj    = lane & 7;
    const int m32   = lane & 31;
    const int khalf = lane >> 5;

    if (wave >= 4) {
        const int pw = wave - 4;
#pragma unroll
        for (int it = 0; it < PA; ++it) {
            const int c  = pw * PA + it;
            const int jg = jj ^ lr ^ (c & 7);
            const size_t aoff = (size_t)(rowBase + c * 8 + lr) * KTOT + jg * 8;
            int4 v;
            if (A_F32) {
                const float* ga = (const float*)Av + aoff;
                float4 f0 = *(const float4*)ga;
                float4 f1 = *(const float4*)(ga + 4);
                v.x = (uint32_t)f2b(f0.x) | ((uint32_t)f2b(f0.y) << 16);
                v.y = (uint32_t)f2b(f0.z) | ((uint32_t)f2b(f0.w) << 16);
                v.z = (uint32_t)f2b(f1.x) | ((uint32_t)f2b(f1.y) << 16);
                v.w = (uint32_t)f2b(f1.z) | ((uint32_t)f2b(f1.w) << 16);
            } else {
                v = *(const int4*)((const unsigned short*)Av + aoff);
            }
            *(int4*)&As[c * 512 + lane * 8] = v;
        }
#pragma unroll
        for (int it = 0; it < PB; ++it) {
            const int c  = pw * PB + it;
            const int jg = jj ^ lr ^ (c & 7);
            *(int4*)&Bs[c * 512 + lane * 8] =
                *(const int4*)(Bt + (size_t)(colBase + c * 8 + lr) * KTOT + jg * 8);
        }
        __syncthreads();

        int buf = 1;
        for (int k0 = BK; k0 < KTOT; k0 += BK) {
            int4 aR[PA], bR[PB];
#pragma unroll
            for (int it = 0; it < PA; ++it) {
                const int c  = pw * PA + it;
                const int jg = jj ^ lr ^ (c & 7);
                const size_t aoff = (size_t)(rowBase + c * 8 + lr) * KTOT + k0 + jg * 8;
                if (A_F32) {
                    const float* ga = (const float*)Av + aoff;
                    float4 f0 = *(const float4*)ga;
                    float4 f1 = *(const float4*)(ga + 4);
                    int4 v;
                    v.x = (uint32_t)f2b(f0.x) | ((uint32_t)f2b(f0.y) << 16);
                    v.y = (uint32_t)f2b(f0.z) | ((uint32_t)f2b(f0.w) << 16);
                    v.z = (uint32_t)f2b(f1.x) | ((uint32_t)f2b(f1.y) << 16);
                    v.w = (uint32_t)f2b(f1.z) | ((uint32_t)f2b(f1.w) << 16);
                    aR[it] = v;
                } else {
                    aR[it] = *(const int4*)((const unsigned short*)Av + aoff);
                }
            }
#pragma unroll
            for (int it = 0; it < PB; ++it) {
                const int c  = pw * PB + it;
                const int jg = jj ^ lr ^ (c & 7);
                bR[it] = *(const int4*)(Bt + (size_t)(colBase + c * 8 + lr) * KTOT + k0 + jg * 8);
            }
#pragma unroll
            for (int it = 0; it < PA; ++it) {
                const int c = pw * PA + it;
                *(int4*)&As[buf * ASZ + c * 512 + lane * 8] = aR[it];
            }
#pragma unroll
            for (int it = 0; it < PB; ++it) {
                const int c = pw * PB + it;
                *(int4*)&Bs[buf * BSZ + c * 512 + lane * 8] = bR[it];
            }
            __syncthreads();
            buf ^= 1;
        }
    } else {
        const int waveM = (wave >> 1) * (BM / 2);
        const int waveN = (wave & 1) * (BN / 2);
        f32x16 acc[FI][FJ] = {};

        __syncthreads();

        int cur = 0;
        for (int k0 = BK; k0 < KTOT; k0 += BK) {
            PC_COMPUTE(cur)
            __syncthreads();
            cur ^= 1;
        }
        PC_COMPUTE(cur)

#pragma unroll
        for (int i = 0; i < FI; ++i) {
#pragma unroll
            for (int j = 0; j < FJ; ++j) {
                const int col = colBase + waveN + j * 32 + m32;
                const float bv = bias[col];
#pragma unroll
                for (int reg = 0; reg < 16; ++reg) {
                    const int row = rowBase + waveM + i * 32 +
                                    (reg & 3) + 8 * (reg >> 2) + 4 * khalf;
                    float z = acc[i][j][reg] + bv;
                    if (DO_GELU)
                        z = 0.5f * z * (1.f + erff(z * 0.70710678118654752f));
                    const size_t off = (size_t)row * Ncols + col;
                    if (C_F32) ((float*)Cv)[off] = z;
                    else       ((unsigned short*)Cv)[off] = f2b(z);
                }
            }
        }
    }
}

// ---------------------------------------------------------------------------
extern "C" void kernel_launch(void* const* d_in, const int* in_sizes, int n_in,
                              void* d_out, int out_size, void* d_ws, size_t ws_size,
                              hipStream_t stream) {
    const float* x      = (const float*)d_in[0];   // [4096,1024] fp32
    const float* fc1_c0 = (const float*)d_in[1];
    const float* fc1_c1 = (const float*)d_in[2];
    const float* fc1_c2 = (const float*)d_in[3];
    const float* fc1_b  = (const float*)d_in[4];
    const float* fc2_c0 = (const float*)d_in[5];
    const float* fc2_c1 = (const float*)d_in[6];
    const float* fc2_c2 = (const float*)d_in[7];
    const float* fc2_b  = (const float*)d_in[8];

    char* ws = (char*)d_ws;
    const bool big = ws_size >= (48ull << 20);

    constexpr int DLDS8 = 3 * (256 + 128) * 64 * 2;  // 144 KB ring (gemm_8p)
    constexpr int DLDS  = 40 << 10;                  // gemm_sb: 4 blocks/CU

    static bool attr_done = false;
    if (!attr_done) {
        attr_done = true;
        (void)hipFuncSetAttribute(
            reinterpret_cast<const void*>(&gemm_8p<256, 128, 1024, 32, true>),
            hipFuncAttributeMaxDynamicSharedMemorySize, DLDS8);
    }

    if (big) {
        // d_out scratch: xb bf16 [0,8M) -- dead before GEMM2 writes d_out.
        // ws: W1 [0,8M), W2 [8,16M), h bf16 [16,48M)
        unsigned short* xb = (unsigned short*)d_out;
        unsigned short* W1 = (unsigned short*)ws;
        unsigned short* W2 = (unsigned short*)(ws + (8u << 20));
        unsigned short* h  = (unsigned short*)(ws + (16u << 20));

        // K0: all pre-GEMM work in one launch (R11-verified)
        prep_all<<<2560, 256, 0, stream>>>(fc1_c0, fc1_c1, fc1_c2,
                                           fc2_c0, fc2_c1, fc2_c2,
                                           x, xb, W1, W2);
        // K1: GEMM1 -- phase-pipelined 256x128, grid 32x16 = 512 blocks
        gemm_8p<256, 128, 1024, 32, true>
            <<<dim3(32, 16), 512, DLDS8, stream>>>(xb, W1, fc1_b, h, 4096);
        // K2: GEMM2 -- R11-proven gemm_sb direct-write
        gemm_sb<128, 64, 4096, 4096, 16, 32, false, false>
            <<<dim3(16, 32, 1), 256, DLDS, stream>>>(h, W2, fc2_b, d_out, 1024);
    } else {
        float* T1 = (float*)d_out;
        float* T2 = (float*)d_out + 524288;
        unsigned short* xb = (unsigned short*)((char*)d_out + (4u << 20));
        unsigned short* W = (unsigned short*)ws;
        unsigned short* h = (unsigned short*)(ws + (8u << 20));

        prep_stage1<<<6144, 256, 0, stream>>>(fc1_c1, fc1_c2, T1,
                                              fc2_c1, fc2_c2, T2, x, xb);
        build_W<8, 16, 8, 16, 16, 16><<<2048, 256, 0, stream>>>(fc1_c0, T1, W);
        gemm_pc<128, 128, 1024, true, false, false>
            <<<dim3(32, 32), 512, 0, stream>>>(xb, W, fc1_b, h, 4096);
        build_W<16, 16, 16, 8, 16, 8><<<1024, 256, 0, stream>>>(fc2_c0, T2, W);
        gemm_pc<128, 64, 4096, false, false, true>
            <<<dim3(16, 32), 512, 0, stream>>>(h, W, fc2_b, d_out, 1024);
    }
}

// Round 13
// 202.683 us; speedup vs baseline: 1.2276x; 1.0412x over previous
//
#include <hip/hip_runtime.h>
#include <stdint.h>

// ---------- bf16 helpers (storage = unsigned short) ----------
__device__ __forceinline__ float b2f(unsigned short u) {
    union { uint32_t i; float f; } v; v.i = ((uint32_t)u) << 16; return v.f;
}
__device__ __forceinline__ unsigned short f2b(float f) {
    union { float f; uint32_t i; } v; v.f = f;
    uint32_t r = v.i + 0x7fffu + ((v.i >> 16) & 1u);   // RNE
    return (unsigned short)(r >> 16);
}

typedef __bf16 bf16x8 __attribute__((ext_vector_type(8)));
typedef float  f32x16 __attribute__((ext_vector_type(16)));

// ---------------------------------------------------------------------------
// build_W_fused + prep_all: ONE launch for all pre-GEMM work (R11-verified).
// ---------------------------------------------------------------------------
template<int N1, int N2, int N3, int M1, int M2, int M3>
__device__ __forceinline__ void build_W_fused(int blk,
                                              const float* __restrict__ c0,
                                              const float* __restrict__ c1,
                                              const float* __restrict__ c2,
                                              unsigned short* __restrict__ W,
                                              float* __restrict__ S) {
    constexpr int K = N1 * N2 * N3;
    const int n2 = blk / M2;
    const int m2 = blk % M2;

    for (int e = threadIdx.x; e < 16 * N3 * M3; e += 256) {
        const int m3 = e % M3;
        const int n3 = (e / M3) % N3;
        const int r1 = e / (M3 * N3);
        const float* c1p = c1 + ((r1 * N2 + n2) * M2 + m2) * 16;
        float s = 0.f;
#pragma unroll
        for (int r2 = 0; r2 < 16; ++r2)
            s += c1p[r2] * c2[(r2 * N3 + n3) * M3 + m3];
        S[e] = s;
    }
    __syncthreads();

    for (int e = threadIdx.x; e < N1 * M1 * M3; e += 256) {
        const int m3 = e % M3;
        const int m1 = (e / M3) % M1;
        const int n1 = e / (M3 * M1);
        const float* c0p = c0 + (n1 * M1 + m1) * 16;
        float acc[N3] = {};
#pragma unroll
        for (int r1 = 0; r1 < 16; ++r1) {
            const float c0v = c0p[r1];
#pragma unroll
            for (int n3 = 0; n3 < N3; ++n3)
                acc[n3] += c0v * S[(r1 * N3 + n3) * M3 + m3];
        }
        unsigned short ob[N3];
#pragma unroll
        for (int n3 = 0; n3 < N3; ++n3) ob[n3] = f2b(acc[n3]);
        unsigned short* dst = W + (size_t)((m1 * M2 + m2) * M3 + m3) * K
                                + (n1 * N2 + n2) * N3;
#pragma unroll
        for (int c = 0; c < N3 / 8; ++c)
            ((int4*)dst)[c] = ((const int4*)ob)[c];
    }
}

__global__ __launch_bounds__(256)
void prep_all(const float* __restrict__ c10, const float* __restrict__ c11,
              const float* __restrict__ c12,
              const float* __restrict__ c20, const float* __restrict__ c21,
              const float* __restrict__ c22,
              const float* __restrict__ x, unsigned short* __restrict__ xb,
              unsigned short* __restrict__ W1, unsigned short* __restrict__ W2) {
    __shared__ float S[16 * 128];
    const int b = blockIdx.x;
    if (b < 256) {
        build_W_fused<8, 16, 8, 16, 16, 16>(b, c10, c11, c12, W1, S);
    } else if (b < 512) {
        build_W_fused<16, 16, 16, 8, 16, 8>(b - 256, c20, c21, c22, W2, S);
    } else {
        const int t = (b - 512) * 256 + threadIdx.x;
        const float4* p = (const float4*)(x + (size_t)t * 8);
        float4 f0 = p[0], f1 = p[1];
        int4 o;
        o.x = (uint32_t)f2b(f0.x) | ((uint32_t)f2b(f0.y) << 16);
        o.y = (uint32_t)f2b(f0.z) | ((uint32_t)f2b(f0.w) << 16);
        o.z = (uint32_t)f2b(f1.x) | ((uint32_t)f2b(f1.y) << 16);
        o.w = (uint32_t)f2b(f1.z) | ((uint32_t)f2b(f1.w) << 16);
        ((int4*)xb)[t] = o;
    }
}

// ---------------------------------------------------------------------------
// Fallback-path kernels (small workspace): verified R5-R7 chain.
// ---------------------------------------------------------------------------
template<int N3, int M3>
__device__ __forceinline__ void build_T_body(int e,
                                             const float* __restrict__ c1,
                                             const float* __restrict__ c2,
                                             float* __restrict__ T) {
    int m3 = e % M3;
    int t  = e / M3;
    int n3 = t % N3;
    int rm = t / N3;
    float s = 0.f;
#pragma unroll
    for (int r2 = 0; r2 < 16; ++r2)
        s += c1[rm * 16 + r2] * c2[(r2 * N3 + n3) * M3 + m3];
    T[e] = s;
}

__global__ __launch_bounds__(256)
void prep_stage1(const float* __restrict__ c11, const float* __restrict__ c12,
                 float* __restrict__ T1,
                 const float* __restrict__ c21, const float* __restrict__ c22,
                 float* __restrict__ T2,
                 const float* __restrict__ x, unsigned short* __restrict__ xb) {
    const int b = blockIdx.x;
    if (b < 2048) {
        build_T_body<8, 16>(b * 256 + threadIdx.x, c11, c12, T1);
    } else if (b < 4096) {
        build_T_body<16, 8>((b - 2048) * 256 + threadIdx.x, c21, c22, T2);
    } else {
        const int t = (b - 4096) * 256 + threadIdx.x;
        const float4* p = (const float4*)(x + (size_t)t * 8);
        float4 f0 = p[0], f1 = p[1];
        int4 o;
        o.x = (uint32_t)f2b(f0.x) | ((uint32_t)f2b(f0.y) << 16);
        o.y = (uint32_t)f2b(f0.z) | ((uint32_t)f2b(f0.w) << 16);
        o.z = (uint32_t)f2b(f1.x) | ((uint32_t)f2b(f1.y) << 16);
        o.w = (uint32_t)f2b(f1.z) | ((uint32_t)f2b(f1.w) << 16);
        ((int4*)xb)[t] = o;
    }
}

template<int N1, int N2, int N3, int M1, int M2, int M3>
__device__ __forceinline__ void build_W_body(int t,
                                             const float* __restrict__ c0,
                                             const float* __restrict__ T,
                                             unsigned short* __restrict__ W) {
    constexpr int K = N1 * N2 * N3;
    int m3 = t % M3;
    int m2 = (t / M3) % M2;
    int n2 = (t / (M3 * M2)) % N2;
    int m1 = (t / (M3 * M2 * N2)) % M1;
    int n1 =  t / (M3 * M2 * N2 * M1);

    float c0r[16];
    const float4* c0p = (const float4*)(c0 + (n1 * M1 + m1) * 16);
#pragma unroll
    for (int i = 0; i < 4; ++i) ((float4*)c0r)[i] = c0p[i];

    float acc[N3] = {};
#pragma unroll
    for (int r1 = 0; r1 < 16; ++r1) {
        const float* Tp = T + (size_t)(((r1 * 16 + n2) * 16 + m2) * N3) * M3 + m3;
#pragma unroll
        for (int n3 = 0; n3 < N3; ++n3)
            acc[n3] += c0r[r1] * Tp[n3 * M3];
    }

    unsigned short ob[N3];
#pragma unroll
    for (int n3 = 0; n3 < N3; ++n3) ob[n3] = f2b(acc[n3]);

    unsigned short* dst = W + (size_t)((m1 * M2 + m2) * M3 + m3) * K
                            + (n1 * N2 + n2) * N3;
#pragma unroll
    for (int c = 0; c < N3 / 8; ++c)
        ((int4*)dst)[c] = ((const int4*)ob)[c];
}

template<int N1, int N2, int N3, int M1, int M2, int M3>
__global__ __launch_bounds__(256)
void build_W(const float* __restrict__ c0, const float* __restrict__ T,
             unsigned short* __restrict__ W) {
    build_W_body<N1, N2, N3, M1, M2, M3>(blockIdx.x * 256 + threadIdx.x, c0, T, W);
}

// ---------------------------------------------------------------------------
// gemm_big: 256x256 tile, 8 waves, 128x64 WAVE TILE -- the R13 change.
//
// R12 finding: six schedules all cap at 22% MfmaUtil because the 64x64 wave
// tile is LDS-READ-BOUND, not schedule-bound: per 128^2 K-tile, 64x
// ds_read_b128 = 768cy/CU vs 516cy MFMA (12cy/b128 at 85B/cy).  The ratio
// is set by wave-tile shape: 128x64 (FI=4,FJ=2) reads 6 frags per 8 MFMA ->
// per 256^2 tile MFMA 2066cy vs LDS-read 2304cy, and staging bytes/FLOP
// halve.  Loop skeleton = R8's proven dbuf: STAGE(buf^1, t+1) -> COMPUTE
// (buf) -> __syncthreads.  The gload_lds issue precedes ~2000cy of MFMA,
// so the barrier drain is mostly covered.  No asm (R6 lesson).
//
// 512 threads = 8 waves as 2(M) x 4(N); acc f32x16[4][2] = 128 VGPR
// (__launch_bounds__(512,2) caps at 256: 2 waves/SIMD).  LDS 2 x 64KB =
// 128KB -> 1 block/CU; grid 16x16 = 256 = one full residency round.
//
// Staging: 8KB issues (512 thr x 16B), srow = tid>>3 (64 rows/issue),
// sslot = tid&7.  Wave-uniform dst = c*4096 + wave*512 elems (rows
// c*64+wave*8..+8 -- same proven formula family as R8/R10).  Pre-swizzled
// source jg = sslot ^ key(r), key(r) = (r&7)^((r>>3)&7) (0-conflict BK=64
// swizzle); read slot = (ks*2+khalf) ^ key(r).
// C/D map (m74/m101): col=lane&31, row=(reg&3)+8*(reg>>2)+4*(lane>>5).
// ---------------------------------------------------------------------------
template<int BM, int BN, int KTOT, int GX, bool DO_GELU>
__global__ __launch_bounds__(512, 2)
void gemm_big(const unsigned short* __restrict__ A,
              const unsigned short* __restrict__ Bt,
              const float* __restrict__ bias,
              unsigned short* __restrict__ C,
              int Ncols)
{
    constexpr int BK   = 64;
    constexpr int NT   = KTOT / BK;
    constexpr int ASZ  = BM * BK;          // 16384 elems (32KB)
    constexpr int BUFE = (BM + BN) * BK;   // 32768 elems (64KB)
    constexpr int ACH  = BM / 64;          // 8KB issues for A tile (4)
    constexpr int BCH  = BN / 64;          // 4
    constexpr int FI   = 4, FJ = 2;        // 128x64 wave tile in 32^2 units

    extern __shared__ unsigned short sh[];   // [2][BUFE]

    const int tid   = threadIdx.x;
    const int lane  = tid & 63;
    const int wave  = tid >> 6;            // 0..7
    const int m32   = lane & 31;
    const int khalf = lane >> 5;
    const int waveM = (wave >> 2) * 128;   // 2 M-waves
    const int waveN = (wave & 3) * 64;     // 4 N-waves
    const int srow  = tid >> 3;            // staging row-within-issue (0..63)
    const int sslot = tid & 7;             // staging 16B slot

    // XCD-chunked bijective block swizzle (total = 256, %8==0)
    int lin = (int)blockIdx.y * GX + (int)blockIdx.x;
    const int total = GX * (int)gridDim.y;
    lin = (lin & 7) * (total >> 3) + (lin >> 3);
    const int colBase = (lin % GX) * BN;
    const int rowBase = (lin / GX) * BM;

#define BG_STAGE(B_, K0_)                                                     \
    {                                                                         \
        _Pragma("unroll")                                                     \
        for (int c = 0; c < ACH; ++c) {                                       \
            const int r  = c * 64 + srow;                                     \
            const int jg = sslot ^ (r & 7) ^ ((r >> 3) & 7);                  \
            const unsigned short* src = A +                                   \
                (size_t)(rowBase + r) * KTOT + (K0_) + jg * 8;                \
            unsigned short* dst = sh + (B_) * BUFE + c * 4096 + wave * 512;   \
            __builtin_amdgcn_global_load_lds(                                 \
                (const __attribute__((address_space(1))) void*)src,           \
                (__attribute__((address_space(3))) void*)dst, 16, 0, 0);      \
        }                                                                     \
        _Pragma("unroll")                                                     \
        for (int c = 0; c < BCH; ++c) {                                       \
            const int r  = c * 64 + srow;                                     \
            const int jg = sslot ^ (r & 7) ^ ((r >> 3) & 7);                  \
            const unsigned short* src = Bt +                                  \
                (size_t)(colBase + r) * KTOT + (K0_) + jg * 8;                \
            unsigned short* dst = sh + (B_) * BUFE + ASZ + c * 4096           \
                                  + wave * 512;                               \
            __builtin_amdgcn_global_load_lds(                                 \
                (const __attribute__((address_space(1))) void*)src,           \
                (__attribute__((address_space(3))) void*)dst, 16, 0, 0);      \
        }                                                                     \
    }

    f32x16 acc[FI][FJ] = {};

    // prologue: stage tile 0 into buf 0 (syncthreads drains vmcnt -> landed)
    BG_STAGE(0, 0)
    __syncthreads();

    int buf = 0;
    for (int t = 0; t < NT; ++t) {
        if (t + 1 < NT) BG_STAGE(buf ^ 1, (t + 1) * BK)

        const unsigned short* Ab = sh + buf * BUFE;
        const unsigned short* Bb = Ab + ASZ;
#pragma unroll
        for (int ks = 0; ks < 4; ++ks) {
            bf16x8 a_f[FI], b_f[FJ];
            const int g = ks * 2 + khalf;
#pragma unroll
            for (int i = 0; i < FI; ++i) {
                const int r = waveM + i * 32 + m32;
                const int key = (r & 7) ^ ((r >> 3) & 7);
                a_f[i] = *(const bf16x8*)&Ab[r * BK + ((g ^ key) << 3)];
            }
#pragma unroll
            for (int j = 0; j < FJ; ++j) {
                const int r = waveN + j * 32 + m32;
                const int key = (r & 7) ^ ((r >> 3) & 7);
                b_f[j] = *(const bf16x8*)&Bb[r * BK + ((g ^ key) << 3)];
            }
#pragma unroll
            for (int i = 0; i < FI; ++i)
#pragma unroll
                for (int j = 0; j < FJ; ++j)
                    acc[i][j] = __builtin_amdgcn_mfma_f32_32x32x16_bf16(
                        a_f[i], b_f[j], acc[i][j], 0, 0, 0);
        }
        __syncthreads();   // drains vmcnt(0): tile t+1 landed; buf reads done
        buf ^= 1;
    }
#undef BG_STAGE

    // epilogue: col=lane&31, row=(reg&3)+8*(reg>>2)+4*(lane>>5)
#pragma unroll
    for (int i = 0; i < FI; ++i) {
#pragma unroll
        for (int j = 0; j < FJ; ++j) {
            const int col = colBase + waveN + j * 32 + m32;
            const float bv = bias[col];
#pragma unroll
            for (int reg = 0; reg < 16; ++reg) {
                const int row = rowBase + waveM + i * 32 +
                                (reg & 3) + 8 * (reg >> 2) + 4 * khalf;
                float z = acc[i][j][reg] + bv;
                if (DO_GELU)
                    z = 0.5f * z * (1.f + erff(z * 0.70710678118654752f));
                C[(size_t)row * Ncols + col] = f2b(z);
            }
        }
    }
}

// ---------------------------------------------------------------------------
// gemm_sb: SINGLE-buffered BK=64 2-barrier loop (R10-R12-verified, GEMM2).
// 40KB LDS request caps occupancy at the gload_lds-safe 4 blocks/CU.
// ---------------------------------------------------------------------------
template<int BM, int BN, int KCH, int KSTR, int GX, int GY,
         bool DO_GELU, bool ATOMIC>
__global__ __launch_bounds__(256, 4)
void gemm_sb(const unsigned short* __restrict__ A,
             const unsigned short* __restrict__ Bt,
             const float* __restrict__ bias,
             void* __restrict__ Cv,
             int Ncols)
{
    constexpr int BK  = 64;
    constexpr int NT  = KCH / BK;
    constexpr int ASZ = BM * BK;
    constexpr int ACH = BM / 32;
    constexpr int BCH = BN / 32;
    constexpr int FI  = BM / 64, FJ = BN / 64;

    extern __shared__ unsigned short sh[];

    const int tid   = threadIdx.x;
    const int lane  = tid & 63;
    const int wave  = tid >> 6;
    const int m32   = lane & 31;
    const int khalf = lane >> 5;
    const int waveM = (wave >> 1) * (BM / 2);
    const int waveN = (wave & 1) * (BN / 2);
    const int srow  = tid >> 3;
    const int sslot = tid & 7;

    int lin = ((int)blockIdx.z * GY + (int)blockIdx.y) * GX + (int)blockIdx.x;
    const int total = GX * GY * (int)gridDim.z;
    lin = (lin & 7) * (total >> 3) + (lin >> 3);
    const int colBase = (lin % GX) * BN;
    const int rowBase = ((lin / GX) % GY) * BM;
    const int kOff    = (lin / (GX * GY)) * KCH;

#define SB_STAGE(K0_)                                                         \
    {                                                                         \
        _Pragma("unroll")                                                     \
        for (int c = 0; c < ACH; ++c) {                                       \
            const int r  = c * 32 + srow;                                     \
            const int jg = sslot ^ (r & 7) ^ ((r >> 3) & 7);                  \
            const unsigned short* src = A +                                   \
                (size_t)(rowBase + r) * KSTR + (K0_) + jg * 8;                \
            unsigned short* dst = sh + c * 2048 + wave * 512;                 \
            __builtin_amdgcn_global_load_lds(                                 \
                (const __attribute__((address_space(1))) void*)src,           \
                (__attribute__((address_space(3))) void*)dst, 16, 0, 0);      \
        }                                                                     \
        _Pragma("unroll")                                                     \
        for (int c = 0; c < BCH; ++c) {                                       \
            const int r  = c * 32 + srow;                                     \
            const int jg = sslot ^ (r & 7) ^ ((r >> 3) & 7);                  \
            const unsigned short* src = Bt +                                  \
                (size_t)(colBase + r) * KSTR + (K0_) + jg * 8;                \
            unsigned short* dst = sh + ASZ + c * 2048 + wave * 512;           \
            __builtin_amdgcn_global_load_lds(                                 \
                (const __attribute__((address_space(1))) void*)src,           \
                (__attribute__((address_space(3))) void*)dst, 16, 0, 0);      \
        }                                                                     \
    }

    f32x16 acc[FI][FJ] = {};

    for (int t = 0; t < NT; ++t) {
        SB_STAGE(kOff + t * BK)
        __syncthreads();

        const unsigned short* Ab = sh;
        const unsigned short* Bb = sh + ASZ;
#pragma unroll
        for (int ks = 0; ks < 4; ++ks) {
            bf16x8 a_f[FI], b_f[FJ];
            const int g = ks * 2 + khalf;
#pragma unroll
            for (int i = 0; i < FI; ++i) {
                const int r = waveM + i * 32 + m32;
                const int key = (r & 7) ^ ((r >> 3) & 7);
                a_f[i] = *(const bf16x8*)&Ab[r * BK + ((g ^ key) << 3)];
            }
#pragma unroll
            for (int j = 0; j < FJ; ++j) {
                const int r = waveN + j * 32 + m32;
                const int key = (r & 7) ^ ((r >> 3) & 7);
                b_f[j] = *(const bf16x8*)&Bb[r * BK + ((g ^ key) << 3)];
            }
#pragma unroll
            for (int i = 0; i < FI; ++i)
#pragma unroll
                for (int j = 0; j < FJ; ++j)
                    acc[i][j] = __builtin_amdgcn_mfma_f32_32x32x16_bf16(
                        a_f[i], b_f[j], acc[i][j], 0, 0, 0);
        }
        if (t + 1 < NT) __syncthreads();
    }
#undef SB_STAGE

#pragma unroll
    for (int i = 0; i < FI; ++i) {
#pragma unroll
        for (int j = 0; j < FJ; ++j) {
            const int col = colBase + waveN + j * 32 + m32;
            const float bv = ATOMIC ? 0.f : bias[col];
#pragma unroll
            for (int reg = 0; reg < 16; ++reg) {
                const int row = rowBase + waveM + i * 32 +
                                (reg & 3) + 8 * (reg >> 2) + 4 * khalf;
                const size_t off = (size_t)row * Ncols + col;
                if (ATOMIC) {
                    unsafeAtomicAdd((float*)Cv + off, acc[i][j][reg]);
                } else {
                    float z = acc[i][j][reg] + bv;
                    if (DO_GELU) {
                        z = 0.5f * z * (1.f + erff(z * 0.70710678118654752f));
                        ((unsigned short*)Cv)[off] = f2b(z);
                    } else {
                        ((float*)Cv)[off] = z;
                    }
                }
            }
        }
    }
}

// ---------------------------------------------------------------------------
// gemm_pc: R0's producer-consumer GEMM (fallback path only).
// ---------------------------------------------------------------------------
#define PC_COMPUTE(BUF)                                                       \
    {                                                                         \
        _Pragma("unroll")                                                     \
        for (int ks = 0; ks < 4; ++ks) {                                      \
            bf16x8 a_f[FI], b_f[FJ];                                          \
            _Pragma("unroll")                                                 \
            for (int i = 0; i < FI; ++i) {                                    \
                const int key = (m32 & 7) ^                                   \
                    (((waveM >> 3) + 4 * i + (m32 >> 3)) & 7);                \
                const int slot = ((ks * 2 + khalf) ^ key) * 8;                \
                a_f[i] = *(const bf16x8*)&As[(BUF) * ASZ +                    \
                          (waveM + i * 32 + m32) * BK + slot];                \
            }                                                                 \
            _Pragma("unroll")                                                 \
            for (int j = 0; j < FJ; ++j) {                                    \
                const int key = (m32 & 7) ^                                   \
                    (((waveN >> 3) + 4 * j + (m32 >> 3)) & 7);                \
                const int slot = ((ks * 2 + khalf) ^ key) * 8;                \
                b_f[j] = *(const bf16x8*)&Bs[(BUF) * BSZ +                    \
                          (waveN + j * 32 + m32) * BK + slot];                \
            }                                                                 \
            _Pragma("unroll")                                                 \
            for (int i = 0; i < FI; ++i)                                      \
                _Pragma("unroll")                                             \
                for (int j = 0; j < FJ; ++j)                                  \
                    acc[i][j] = __builtin_amdgcn_mfma_f32_32x32x16_bf16(      \
                        a_f[i], b_f[j], acc[i][j], 0, 0, 0);                  \
        }                                                                     \
    }

template<int BM, int BN, int KTOT, bool DO_GELU, bool A_F32, bool C_F32>
__global__ __launch_bounds__(512, 4)
void gemm_pc(const void* __restrict__ Av,
             const unsigned short* __restrict__ Bt,
             const float* __restrict__ bias,
             void* __restrict__ Cv,
             int Ncols) {
    constexpr int BK  = 64;
    constexpr int CA  = BM / 8;
    constexpr int CB  = BN / 8;
    constexpr int PA  = CA / 4;
    constexpr int PB  = CB / 4;
    constexpr int FI  = BM / 64;
    constexpr int FJ  = BN / 64;
    constexpr int ASZ = BM * BK;
    constexpr int BSZ = BN * BK;
    __shared__ unsigned short As[2 * ASZ];
    __shared__ unsigned short Bs[2 * BSZ];

    const int tid  = threadIdx.x;
    const int lane = tid & 63;
    const int wave = tid >> 6;
    const int rowBase = blockIdx.y * BM;
    const int colBase = blockIdx.x * BN;

    const int lr    = lane >> 3;
    const int jj    = lane & 7;
    const int m32   = lane & 31;
    const int khalf = lane >> 5;

    if (wave >= 4) {
        const int pw = wave - 4;
#pragma unroll
        for (int it = 0; it < PA; ++it) {
            const int c  = pw * PA + it;
            const int jg = jj ^ lr ^ (c & 7);
            const size_t aoff = (size_t)(rowBase + c * 8 + lr) * KTOT + jg * 8;
            int4 v;
            if (A_F32) {
                const float* ga = (const float*)Av + aoff;
                float4 f0 = *(const float4*)ga;
                float4 f1 = *(const float4*)(ga + 4);
                v.x = (uint32_t)f2b(f0.x) | ((uint32_t)f2b(f0.y) << 16);
                v.y = (uint32_t)f2b(f0.z) | ((uint32_t)f2b(f0.w) << 16);
                v.z = (uint32_t)f2b(f1.x) | ((uint32_t)f2b(f1.y) << 16);
                v.w = (uint32_t)f2b(f1.z) | ((uint32_t)f2b(f1.w) << 16);
            } else {
                v = *(const int4*)((const unsigned short*)Av + aoff);
            }
            *(int4*)&As[c * 512 + lane * 8] = v;
        }
#pragma unroll
        for (int it = 0; it < PB; ++it) {
            const int c  = pw * PB + it;
            const int jg = jj ^ lr ^ (c & 7);
            *(int4*)&Bs[c * 512 + lane * 8] =
                *(const int4*)(Bt + (size_t)(colBase + c * 8 + lr) * KTOT + jg * 8);
        }
        __syncthreads();

        int buf = 1;
        for (int k0 = BK; k0 < KTOT; k0 += BK) {
            int4 aR[PA], bR[PB];
#pragma unroll
            for (int it = 0; it < PA; ++it) {
                const int c  = pw * PA + it;
                const int jg = jj ^ lr ^ (c & 7);
                const size_t aoff = (size_t)(rowBase + c * 8 + lr) * KTOT + k0 + jg * 8;
                if (A_F32) {
                    const float* ga = (const float*)Av + aoff;
                    float4 f0 = *(const float4*)ga;
                    float4 f1 = *(const float4*)(ga + 4);
                    int4 v;
                    v.x = (uint32_t)f2b(f0.x) | ((uint32_t)f2b(f0.y) << 16);
                    v.y = (uint32_t)f2b(f0.z) | ((uint32_t)f2b(f0.w) << 16);
                    v.z = (uint32_t)f2b(f1.x) | ((uint32_t)f2b(f1.y) << 16);
                    v.w = (uint32_t)f2b(f1.z) | ((uint32_t)f2b(f1.w) << 16);
                    aR[it] = v;
                } else {
                    aR[it] = *(const int4*)((const unsigned short*)Av + aoff);
                }
            }
#pragma unroll
            for (int it = 0; it < PB; ++it) {
                const int c  = pw * PB + it;
                const int jg = jj ^ lr ^ (c & 7);
                bR[it] = *(const int4*)(Bt + (size_t)(colBase + c * 8 + lr) * KTOT + k0 + jg * 8);
            }
#pragma unroll
            for (int it = 0; it < PA; ++it) {
                const int c = pw * PA + it;
                *(int4*)&As[buf * ASZ + c * 512 + lane * 8] = aR[it];
            }
#pragma unroll
            for (int it = 0; it < PB; ++it) {
                const int c = pw * PB + it;
                *(int4*)&Bs[buf * BSZ + c * 512 + lane * 8] = bR[it];
            }
            __syncthreads();
            buf ^= 1;
        }
    } else {
        const int waveM = (wave >> 1) * (BM / 2);
        const int waveN = (wave & 1) * (BN / 2);
        f32x16 acc[FI][FJ] = {};

        __syncthreads();

        int cur = 0;
        for (int k0 = BK; k0 < KTOT; k0 += BK) {
            PC_COMPUTE(cur)
            __syncthreads();
            cur ^= 1;
        }
        PC_COMPUTE(cur)

#pragma unroll
        for (int i = 0; i < FI; ++i) {
#pragma unroll
            for (int j = 0; j < FJ; ++j) {
                const int col = colBase + waveN + j * 32 + m32;
                const float bv = bias[col];
#pragma unroll
                for (int reg = 0; reg < 16; ++reg) {
                    const int row = rowBase + waveM + i * 32 +
                                    (reg & 3) + 8 * (reg >> 2) + 4 * khalf;
                    float z = acc[i][j][reg] + bv;
                    if (DO_GELU)
                        z = 0.5f * z * (1.f + erff(z * 0.70710678118654752f));
                    const size_t off = (size_t)row * Ncols + col;
                    if (C_F32) ((float*)Cv)[off] = z;
                    else       ((unsigned short*)Cv)[off] = f2b(z);
                }
            }
        }
    }
}

// ---------------------------------------------------------------------------
extern "C" void kernel_launch(void* const* d_in, const int* in_sizes, int n_in,
                              void* d_out, int out_size, void* d_ws, size_t ws_size,
                              hipStream_t stream) {
    const float* x      = (const float*)d_in[0];   // [4096,1024] fp32
    const float* fc1_c0 = (const float*)d_in[1];
    const float* fc1_c1 = (const float*)d_in[2];
    const float* fc1_c2 = (const float*)d_in[3];
    const float* fc1_b  = (const float*)d_in[4];
    const float* fc2_c0 = (const float*)d_in[5];
    const float* fc2_c1 = (const float*)d_in[6];
    const float* fc2_c2 = (const float*)d_in[7];
    const float* fc2_b  = (const float*)d_in[8];

    char* ws = (char*)d_ws;
    const bool big = ws_size >= (48ull << 20);

    constexpr int DLDSB = 2 * (256 + 256) * 64 * 2;  // 128 KB dbuf (gemm_big)
    constexpr int DLDS  = 40 << 10;                  // gemm_sb: 4 blocks/CU

    static bool attr_done = false;
    if (!attr_done) {
        attr_done = true;
        (void)hipFuncSetAttribute(
            reinterpret_cast<const void*>(&gemm_big<256, 256, 1024, 16, true>),
            hipFuncAttributeMaxDynamicSharedMemorySize, DLDSB);
    }

    if (big) {
        // d_out scratch: xb bf16 [0,8M) -- dead before GEMM2 writes d_out.
        // ws: W1 [0,8M), W2 [8,16M), h bf16 [16,48M)
        unsigned short* xb = (unsigned short*)d_out;
        unsigned short* W1 = (unsigned short*)ws;
        unsigned short* W2 = (unsigned short*)(ws + (8u << 20));
        unsigned short* h  = (unsigned short*)(ws + (16u << 20));

        // K0: all pre-GEMM work in one launch (R11-verified)
        prep_all<<<2560, 256, 0, stream>>>(fc1_c0, fc1_c1, fc1_c2,
                                           fc2_c0, fc2_c1, fc2_c2,
                                           x, xb, W1, W2);
        // K1: GEMM1 -- 256x256 tile, 128x64 wave tile, grid 16x16 = 256
        gemm_big<256, 256, 1024, 16, true>
            <<<dim3(16, 16), 512, DLDSB, stream>>>(xb, W1, fc1_b, h, 4096);
        // K2: GEMM2 -- R11-proven gemm_sb direct-write
        gemm_sb<128, 64, 4096, 4096, 16, 32, false, false>
            <<<dim3(16, 32, 1), 256, DLDS, stream>>>(h, W2, fc2_b, d_out, 1024);
    } else {
        float* T1 = (float*)d_out;
        float* T2 = (float*)d_out + 524288;
        unsigned short* xb = (unsigned short*)((char*)d_out + (4u << 20));
        unsigned short* W = (unsigned short*)ws;
        unsigned short* h = (unsigned short*)(ws + (8u << 20));

        prep_stage1<<<6144, 256, 0, stream>>>(fc1_c1, fc1_c2, T1,
                                              fc2_c1, fc2_c2, T2, x, xb);
        build_W<8, 16, 8, 16, 16, 16><<<2048, 256, 0, stream>>>(fc1_c0, T1, W);
        gemm_pc<128, 128, 1024, true, false, false>
            <<<dim3(32, 32), 512, 0, stream>>>(xb, W, fc1_b, h, 4096);
        build_W<16, 16, 16, 8, 16, 8><<<1024, 256, 0, stream>>>(fc2_c0, T2, W);
        gemm_pc<128, 64, 4096, false, false, true>
            <<<dim3(16, 32), 512, 0, stream>>>(h, W, fc2_b, d_out, 1024);
    }
}